// Round 7
// baseline (2524.599 us; speedup 1.0000x reference)
//
#include <hip/hip_runtime.h>

#define HDIM 256
#define EPSV 1e-5f
#define SLOPEV 0.01f

typedef __bf16 bf16;
typedef bf16  bf16x8 __attribute__((ext_vector_type(8)));
typedef bf16  bf16x4 __attribute__((ext_vector_type(4)));
typedef float f32x4  __attribute__((ext_vector_type(4)));

#define GLD16(g, l) __builtin_amdgcn_global_load_lds( \
    (const __attribute__((address_space(1))) void*)(g), \
    (__attribute__((address_space(3))) void*)(l), 16, 0, 0)

// ================= MFMA GEMM =================
// out = concat_k(A0..A_{nseg-1}) * Wt^T + bias (+addb residual).
// Coalesced bf16 epilogue via LDS staging; optional fused column stats
// (sum/sumsq of stored values, rows < n_stats) into pre-zeroed ostats.
template<bool STORE_BF16>
__global__ __launch_bounds__(256)
void gemm_bt_k(const bf16* A0, const bf16* A1, const bf16* A2, const bf16* A3,
               int nseg, int segK,
               const bf16* __restrict__ Wt,
               const float* __restrict__ bias, const bf16* __restrict__ addb,
               void* out0, void* out1, void* out2, void* out3, int ldo,
               int n_store, float* ostats, int Kostat, int n_stats)
{
    __shared__ char smem[17408];
    bf16* As = (bf16*)smem;              // [128][32] bf16, 8 KB
    bf16* Bs = (bf16*)(smem + 8192);     // [128][32] bf16, 8 KB

    const int tid = threadIdx.x;
    const int wave = tid >> 6, lane = tid & 63;
    const int quad = lane >> 4, l16 = lane & 15;
    const int waveM = (wave >> 1) * 64, waveN = (wave & 1) * 64;
    const int bm = blockIdx.y * 128, bn = blockIdx.x * 128;
    const int K = nseg * segK;

    const bf16* segs[4] = {A0, A1, A2, A3};
    char* lA0 = (char*)As + wave * 1024;
    char* lA1 = (char*)As + 4096 + wave * 1024;
    char* lB0 = (char*)Bs + wave * 1024;
    char* lB1 = (char*)Bs + 4096 + wave * 1024;
    const bf16* pa = As + (waveM + l16) * 32 + quad * 8;
    const bf16* pb = Bs + (waveN + l16) * 32 + quad * 8;

    f32x4 acc[4][4] = {};

    for (int s = 0; s < nseg; ++s) {
        const bf16* A = segs[s];
        const bf16* gA0 = A + (size_t)(bm + (tid >> 2)) * segK + (tid & 3) * 8;
        const bf16* gA1 = A + (size_t)(bm + 64 + (tid >> 2)) * segK + (tid & 3) * 8;
        const bf16* gB0 = Wt + (size_t)(bn + (tid >> 2)) * K + s * segK + (tid & 3) * 8;
        const bf16* gB1 = Wt + (size_t)(bn + 64 + (tid >> 2)) * K + s * segK + (tid & 3) * 8;
        for (int kt = 0; kt < segK; kt += 32) {
            GLD16(gA0, lA0); GLD16(gA1, lA1);
            GLD16(gB0, lB0); GLD16(gB1, lB1);
            gA0 += 32; gA1 += 32; gB0 += 32; gB1 += 32;
            __syncthreads();

            bf16x8 a0 = *(const bf16x8*)(pa);
            bf16x8 a1 = *(const bf16x8*)(pa + 16 * 32);
            bf16x8 a2 = *(const bf16x8*)(pa + 32 * 32);
            bf16x8 a3 = *(const bf16x8*)(pa + 48 * 32);
            bf16x8 b0 = *(const bf16x8*)(pb);
            bf16x8 b1 = *(const bf16x8*)(pb + 16 * 32);
            bf16x8 b2 = *(const bf16x8*)(pb + 32 * 32);
            bf16x8 b3 = *(const bf16x8*)(pb + 48 * 32);

            acc[0][0] = __builtin_amdgcn_mfma_f32_16x16x32_bf16(a0, b0, acc[0][0], 0, 0, 0);
            acc[0][1] = __builtin_amdgcn_mfma_f32_16x16x32_bf16(a0, b1, acc[0][1], 0, 0, 0);
            acc[0][2] = __builtin_amdgcn_mfma_f32_16x16x32_bf16(a0, b2, acc[0][2], 0, 0, 0);
            acc[0][3] = __builtin_amdgcn_mfma_f32_16x16x32_bf16(a0, b3, acc[0][3], 0, 0, 0);
            acc[1][0] = __builtin_amdgcn_mfma_f32_16x16x32_bf16(a1, b0, acc[1][0], 0, 0, 0);
            acc[1][1] = __builtin_amdgcn_mfma_f32_16x16x32_bf16(a1, b1, acc[1][1], 0, 0, 0);
            acc[1][2] = __builtin_amdgcn_mfma_f32_16x16x32_bf16(a1, b2, acc[1][2], 0, 0, 0);
            acc[1][3] = __builtin_amdgcn_mfma_f32_16x16x32_bf16(a1, b3, acc[1][3], 0, 0, 0);
            acc[2][0] = __builtin_amdgcn_mfma_f32_16x16x32_bf16(a2, b0, acc[2][0], 0, 0, 0);
            acc[2][1] = __builtin_amdgcn_mfma_f32_16x16x32_bf16(a2, b1, acc[2][1], 0, 0, 0);
            acc[2][2] = __builtin_amdgcn_mfma_f32_16x16x32_bf16(a2, b2, acc[2][2], 0, 0, 0);
            acc[2][3] = __builtin_amdgcn_mfma_f32_16x16x32_bf16(a2, b3, acc[2][3], 0, 0, 0);
            acc[3][0] = __builtin_amdgcn_mfma_f32_16x16x32_bf16(a3, b0, acc[3][0], 0, 0, 0);
            acc[3][1] = __builtin_amdgcn_mfma_f32_16x16x32_bf16(a3, b1, acc[3][1], 0, 0, 0);
            acc[3][2] = __builtin_amdgcn_mfma_f32_16x16x32_bf16(a3, b2, acc[3][2], 0, 0, 0);
            acc[3][3] = __builtin_amdgcn_mfma_f32_16x16x32_bf16(a3, b3, acc[3][3], 0, 0, 0);
            __syncthreads();
        }
    }

    float bv[4];
#pragma unroll
    for (int j = 0; j < 4; ++j)
        bv[j] = bias ? bias[bn + waveN + j * 16 + l16] : 0.f;
#pragma unroll
    for (int i = 0; i < 4; ++i)
#pragma unroll
        for (int j = 0; j < 4; ++j)
#pragma unroll
            for (int r = 0; r < 4; ++r)
                acc[i][j][r] += bv[j];

    void* outs[4] = {out0, out1, out2, out3};

    if (STORE_BF16) {
        // per-wave 32x64 staging tile, row stride 68 bf16
        char* stg = smem + wave * 4352;
        float s8[8] = {}, q8[8] = {};
        const int rsel = lane >> 3, csel = lane & 7;
#pragma unroll
        for (int ih = 0; ih < 2; ++ih) {
            __syncthreads();
#pragma unroll
            for (int iw = 0; iw < 2; ++iw) {
                int i = ih * 2 + iw;
#pragma unroll
                for (int j = 0; j < 4; ++j)
#pragma unroll
                    for (int r = 0; r < 4; ++r)
                        *(bf16*)(stg + ((iw * 16 + quad * 4 + r) * 68 + j * 16 + l16) * 2)
                            = (bf16)acc[i][j][r];
            }
            __syncthreads();
#pragma unroll
            for (int rr = 0; rr < 4; ++rr) {
                int rl = rsel + rr * 8;
                bf16x4 lo = *(const bf16x4*)(stg + (rl * 68 + csel * 8) * 2);
                bf16x4 hi = *(const bf16x4*)(stg + (rl * 68 + csel * 8 + 4) * 2);
                int rowg = bm + waveM + ih * 32 + rl;
                int colg = bn + waveN + csel * 8;
                int cseg = colg >> 8, cloc = colg & 255;
                size_t idx = (size_t)rowg * ldo + cloc;
                float f[8];
#pragma unroll
                for (int u = 0; u < 4; ++u) { f[u] = (float)lo[u]; f[4 + u] = (float)hi[u]; }
                if (addb) {
                    bf16x8 o = *(const bf16x8*)(addb + idx);
#pragma unroll
                    for (int u = 0; u < 8; ++u) f[u] += (float)o[u];
                }
                bf16x8 w;
#pragma unroll
                for (int u = 0; u < 8; ++u) w[u] = (bf16)f[u];
                if (rowg < n_store) *(bf16x8*)((bf16*)outs[cseg] + idx) = w;
                if (ostats && rowg < n_stats) {
#pragma unroll
                    for (int u = 0; u < 8; ++u) { s8[u] += f[u]; q8[u] += f[u] * f[u]; }
                }
            }
        }
        if (ostats) {
#pragma unroll
            for (int m = 8; m <= 32; m <<= 1)
#pragma unroll
                for (int u = 0; u < 8; ++u) {
                    s8[u] += __shfl_xor(s8[u], m, 64);
                    q8[u] += __shfl_xor(q8[u], m, 64);
                }
            if (rsel == 0) {
                int colg = bn + waveN + csel * 8;
#pragma unroll
                for (int u = 0; u < 8; ++u) {
                    unsafeAtomicAdd(&ostats[colg + u], s8[u]);
                    unsafeAtomicAdd(&ostats[Kostat + colg + u], q8[u]);
                }
            }
        }
    } else {
#pragma unroll
        for (int i = 0; i < 4; ++i)
#pragma unroll
            for (int j = 0; j < 4; ++j) {
                int colg = bn + waveN + j * 16 + l16;
                int cseg = colg >> 8, cloc = colg & 255;
#pragma unroll
                for (int r = 0; r < 4; ++r) {
                    int rowg = bm + waveM + i * 16 + quad * 4 + r;
                    if (rowg < n_store)
                        ((float*)outs[cseg])[(size_t)rowg * ldo + cloc] = acc[i][j][r];
                }
            }
    }
}

// ================= transpose+convert =================
__global__ __launch_bounds__(256)
void transpose_cvt_k(const float* __restrict__ src, bf16* __restrict__ dst,
                     int Kseg, int M, int G)
{
    __shared__ float t[32][33];
    const int z = blockIdx.z;
    src += (size_t)z * Kseg * M;
    const int ldd = G * Kseg;
    dst += (size_t)(z / G) * M * ldd + (size_t)(z % G) * Kseg;
    const int tM = blockIdx.x * 32, tK = blockIdx.y * 32;
    const int tx = threadIdx.x & 31, ty = threadIdx.x >> 5;
#pragma unroll
    for (int r = 0; r < 4; ++r)
        t[ty + r * 8][tx] = src[(size_t)(tK + ty + r * 8) * M + tM + tx];
    __syncthreads();
#pragma unroll
    for (int r = 0; r < 4; ++r)
        dst[(size_t)(tM + ty + r * 8) * ldd + tK + tx] = (bf16)t[tx][ty + r * 8];
}

__global__ __launch_bounds__(256)
void cvt_bf_k(const float* __restrict__ src, bf16* __restrict__ dst, long n4)
{
    long i = (long)blockIdx.x * blockDim.x + threadIdx.x;
    if (i >= n4) return;
    float4 v = ((const float4*)src)[i];
    bf16x4 o; o[0] = (bf16)v.x; o[1] = (bf16)v.y; o[2] = (bf16)v.z; o[3] = (bf16)v.w;
    ((bf16x4*)dst)[i] = o;
}

// ================= CSR build =================
__global__ __launch_bounds__(256)
void deg_k(const int* __restrict__ dst, int* __restrict__ deg, int E)
{
    int e = blockIdx.x * blockDim.x + threadIdx.x;
    if (e < E) atomicAdd(&deg[dst[e]], 1);
}

__global__ __launch_bounds__(1024)
void scan_k(int* __restrict__ deg_wp, int* __restrict__ rowptr, int N)
{
    __shared__ int s[1024];
    const int tid = threadIdx.x;
    if (tid == 0) rowptr[0] = 0;
    int running = 0;
    for (int base = 0; base < N; base += 1024) {
        int i = base + tid;
        int x = (i < N) ? deg_wp[i] : 0;
        s[tid] = x;
        __syncthreads();
        for (int off = 1; off < 1024; off <<= 1) {
            int t = (tid >= off) ? s[tid - off] : 0;
            __syncthreads();
            s[tid] += t;
            __syncthreads();
        }
        if (i < N) {
            rowptr[i + 1] = s[tid] + running;
            deg_wp[i]     = s[tid] + running - x;
        }
        running += s[1023];
        __syncthreads();
    }
}

__global__ __launch_bounds__(256)
void reorder_k(const int* __restrict__ src, const int* __restrict__ dst,
               const float* __restrict__ ew, int* __restrict__ wp,
               int* __restrict__ col, float* __restrict__ wgt, int E)
{
    int e = blockIdx.x * blockDim.x + threadIdx.x;
    if (e >= E) return;
    int d = dst[e];
    int pos = atomicAdd(&wp[d], 1);
    col[pos] = src[e];
    wgt[pos] = ew[e];
}

// ================= pull SpMM (bf16 features, fp32 accum) =================
__global__ __launch_bounds__(256)
void spmm_pull_k(const bf16* __restrict__ P, const int* __restrict__ rowptr,
                 const int* __restrict__ col, const float* __restrict__ wgt,
                 bf16* __restrict__ Q, int N)
{
    int node = blockIdx.x * 4 + (threadIdx.x >> 6);
    int lane = threadIdx.x & 63;
    if (node >= N) return;
    int e = rowptr[node], end = rowptr[node + 1];
    float ax = 0.f, ay = 0.f, az = 0.f, aw = 0.f;
    for (; e + 1 < end; e += 2) {
        int   s0 = col[e], s1 = col[e + 1];
        float w0 = wgt[e], w1 = wgt[e + 1];
        bf16x4 v0 = *(const bf16x4*)(P + (size_t)s0 * HDIM + lane * 4);
        bf16x4 v1 = *(const bf16x4*)(P + (size_t)s1 * HDIM + lane * 4);
        ax += (float)v0[0] * w0 + (float)v1[0] * w1;
        ay += (float)v0[1] * w0 + (float)v1[1] * w1;
        az += (float)v0[2] * w0 + (float)v1[2] * w1;
        aw += (float)v0[3] * w0 + (float)v1[3] * w1;
    }
    if (e < end) {
        int s0 = col[e]; float w0 = wgt[e];
        bf16x4 v0 = *(const bf16x4*)(P + (size_t)s0 * HDIM + lane * 4);
        ax += (float)v0[0] * w0; ay += (float)v0[1] * w0;
        az += (float)v0[2] * w0; aw += (float)v0[3] * w0;
    }
    bf16x4 o; o[0] = (bf16)ax; o[1] = (bf16)ay; o[2] = (bf16)az; o[3] = (bf16)aw;
    *(bf16x4*)(Q + (size_t)node * HDIM + lane * 4) = o;
}

// ================= BN apply (fused finalize from raw stats) =================
__global__ __launch_bounds__(256)
void apply_bn_k(const bf16* __restrict__ X, const float* __restrict__ s,
                const float* __restrict__ g, const float* __restrict__ bb,
                bf16* __restrict__ Y, int n, float invn)
{
    __shared__ float aL[256], bL[256];
    const int tid = threadIdx.x;
    {
        float mean = s[tid] * invn;
        float var  = s[256 + tid] * invn - mean * mean;
        float a = g[tid] * rsqrtf(var + EPSV);
        aL[tid] = a; bL[tid] = bb[tid] - mean * a;
    }
    __syncthreads();
    long n4 = (long)n * 64;
    for (long i = (long)blockIdx.x * 256 + tid; i < n4; i += (long)gridDim.x * 256) {
        bf16x4 v = ((const bf16x4*)X)[i];
        int c4 = (int)(i & 63) * 4;
        float r0 = fmaf((float)v[0], aL[c4 + 0], bL[c4 + 0]); r0 = r0 > 0.f ? r0 : SLOPEV * r0;
        float r1 = fmaf((float)v[1], aL[c4 + 1], bL[c4 + 1]); r1 = r1 > 0.f ? r1 : SLOPEV * r1;
        float r2 = fmaf((float)v[2], aL[c4 + 2], bL[c4 + 2]); r2 = r2 > 0.f ? r2 : SLOPEV * r2;
        float r3 = fmaf((float)v[3], aL[c4 + 3], bL[c4 + 3]); r3 = r3 > 0.f ? r3 : SLOPEV * r3;
        bf16x4 o; o[0] = (bf16)r0; o[1] = (bf16)r1; o[2] = (bf16)r2; o[3] = (bf16)r3;
        ((bf16x4*)Y)[i] = o;
    }
}

__global__ __launch_bounds__(256)
void apply_bn4_k(bf16* X0, bf16* X1, bf16* X2, bf16* X3,
                 const float* __restrict__ s, const float* __restrict__ g,
                 const float* __restrict__ bb, int n, float invn)
{
    __shared__ float aL[1024], bL[1024];
    const int tid = threadIdx.x;
#pragma unroll
    for (int q = 0; q < 4; ++q) {
        int c = q * 256 + tid;
        float mean = s[c] * invn;
        float var  = s[1024 + c] * invn - mean * mean;
        float a = g[c] * rsqrtf(var + EPSV);
        aL[c] = a; bL[c] = bb[c] - mean * a;
    }
    __syncthreads();
    bf16* Xs[4] = {X0, X1, X2, X3};
    long per = (long)n * 64;
    long stride = (long)gridDim.x * 256;
    for (int q = 0; q < 4; ++q) {
        bf16* X = Xs[q];
        int cbase = q * 256;
        for (long i = (long)blockIdx.x * 256 + tid; i < per; i += stride) {
            bf16x4 v = ((const bf16x4*)X)[i];
            int c4 = cbase + (int)(i & 63) * 4;
            float r0 = fmaf((float)v[0], aL[c4 + 0], bL[c4 + 0]); r0 = r0 > 0.f ? r0 : SLOPEV * r0;
            float r1 = fmaf((float)v[1], aL[c4 + 1], bL[c4 + 1]); r1 = r1 > 0.f ? r1 : SLOPEV * r1;
            float r2 = fmaf((float)v[2], aL[c4 + 2], bL[c4 + 2]); r2 = r2 > 0.f ? r2 : SLOPEV * r2;
            float r3 = fmaf((float)v[3], aL[c4 + 3], bL[c4 + 3]); r3 = r3 > 0.f ? r3 : SLOPEV * r3;
            bf16x4 o; o[0] = (bf16)r0; o[1] = (bf16)r1; o[2] = (bf16)r2; o[3] = (bf16)r3;
            ((bf16x4*)X)[i] = o;
        }
    }
}

// ================= host =================
struct GemmArgs {
    const bf16 *A0, *A1, *A2, *A3; int nseg, segK;
    const bf16* Wt; const float* bias; const bf16* addb;
    void *o0, *o1, *o2, *o3; int ldo, M, n_store;
    float* ostats; int Kostat, n_stats;
};

static void gemm(hipStream_t st, const GemmArgs& a, int GY, bool store_bf16)
{
    dim3 g(a.M / 128, GY), b(256);
    if (store_bf16)
        gemm_bt_k<true><<<g, b, 0, st>>>(a.A0, a.A1, a.A2, a.A3, a.nseg, a.segK,
            a.Wt, a.bias, a.addb, a.o0, a.o1, a.o2, a.o3, a.ldo, a.n_store,
            a.ostats, a.Kostat, a.n_stats);
    else
        gemm_bt_k<false><<<g, b, 0, st>>>(a.A0, a.A1, a.A2, a.A3, a.nseg, a.segK,
            a.Wt, a.bias, a.addb, a.o0, a.o1, a.o2, a.o3, a.ldo, a.n_store,
            a.ostats, a.Kostat, a.n_stats);
}

extern "C" void kernel_launch(void* const* d_in, const int* in_sizes, int n_in,
                              void* d_out, int out_size, void* d_ws, size_t ws_size,
                              hipStream_t stream)
{
    const float* x       = (const float*)d_in[0];
    const int*   ei      = (const int*)d_in[1];
    const float* ew      = (const float*)d_in[2];
    const float* W_emb   = (const float*)d_in[3];
    const float* b_emb   = (const float*)d_in[4];
    const float* conv0_W = (const float*)d_in[5];
    const float* conv0_b = (const float*)d_in[6];
    const float* norm_g  = (const float*)d_in[7];
    const float* norm_b  = (const float*)d_in[8];
    const float* conv_W  = (const float*)d_in[9];
    const float* conv_b  = (const float*)d_in[10];
    const float* mlp_W1  = (const float*)d_in[11];
    const float* mlp_b1  = (const float*)d_in[12];
    const float* mlp_g   = (const float*)d_in[13];
    const float* mlp_bb  = (const float*)d_in[14];
    const float* mlp_W2  = (const float*)d_in[15];
    const float* mlp_b2  = (const float*)d_in[16];
    const float* W_out   = (const float*)d_in[17];
    const float* b_out   = (const float*)d_in[18];

    const int N = in_sizes[0] / 128;          // 50000
    const int E = in_sizes[2];                // 800000
    const int* srcI = ei;
    const int* dstI = ei + E;
    const int N_pad = ((N + 127) / 128) * 128;
    const int GY = N_pad / 128;

    const size_t NHp = (size_t)N_pad * HDIM;
    bf16* xb = (bf16*)d_ws;                      // N_pad x 128
    bf16* hb = xb + (size_t)N_pad * 128;
    bf16* cb = hb + NHp;
    bf16* p1 = cb + NHp;
    bf16* p2 = p1 + NHp;
    bf16* e1 = p2 + NHp;                         // doubles as zb
    bf16* e2 = e1 + NHp;
    bf16* wa = e2 + NHp;                         // weight arena
    bf16* Wt_emb   = wa;
    bf16* Wt_conv0 = wa + 32768;
    bf16* Wt_conv  = wa + 229376;
    bf16* Wt_mlp1  = wa + 819200;
    bf16* Wt_mlp2  = wa + 1605632;
    bf16* Wt_out   = wa + 2392064;
    float* sh     = (float*)(wa + 2424832);      // 4 slots x 512
    float* sm     = sh + 2048;                   // 3 slots x 2048
    int*   rowptr = (int*)(sm + 6144);
    int*   wp     = rowptr + (N + 1);
    int*   col    = wp + N;
    float* wgt    = (float*)(col + E);

    const float invn = 1.0f / (float)N;
    dim3 pg((N + 3) / 4), pb(256);

    // ---- CSR build ----
    hipMemsetAsync(wp, 0, (size_t)N * 4, stream);
    deg_k<<<dim3((E + 255) / 256), dim3(256), 0, stream>>>(dstI, wp, E);
    scan_k<<<dim3(1), dim3(1024), 0, stream>>>(wp, rowptr, N);
    reorder_k<<<dim3((E + 255) / 256), dim3(256), 0, stream>>>(srcI, dstI, ew, wp, col, wgt, E);

    // ---- zero stats slots ----
    hipMemsetAsync(sh, 0, 8192 * 4, stream);

    // ---- convert inputs/weights ----
    cvt_bf_k<<<dim3((N * 32 + 255) / 256), dim3(256), 0, stream>>>(x, xb, (long)N * 32);
    transpose_cvt_k<<<dim3(8, 4, 1), dim3(256), 0, stream>>>(W_emb, Wt_emb, 128, 256, 1);
    transpose_cvt_k<<<dim3(8, 8, 3), dim3(256), 0, stream>>>(conv0_W, Wt_conv0, 256, 256, 3);
    transpose_cvt_k<<<dim3(8, 8, 9), dim3(256), 0, stream>>>(conv_W, Wt_conv, 256, 256, 3);
    transpose_cvt_k<<<dim3(32, 8, 3), dim3(256), 0, stream>>>(mlp_W1, Wt_mlp1, 256, 1024, 1);
    transpose_cvt_k<<<dim3(8, 32, 3), dim3(256), 0, stream>>>(mlp_W2, Wt_mlp2, 1024, 256, 1);
    transpose_cvt_k<<<dim3(4, 8, 1), dim3(256), 0, stream>>>(W_out, Wt_out, 256, 128, 1);

    // ---- embed: cb = bf16(x @ W_emb + b_emb) ----
    {
        GemmArgs a{xb, xb, xb, xb, 1, 128, Wt_emb, b_emb, nullptr,
                   cb, cb, cb, cb, HDIM, 256, N_pad, nullptr, 0, 0};
        gemm(stream, a, GY, true);
    }

    // ---- conv0: hb = [cb | A.cb | A^2.cb] @ Wt_conv0 + b ; stats -> sh[0] ----
    spmm_pull_k<<<pg, pb, 0, stream>>>(cb, rowptr, col, wgt, p1, N);
    spmm_pull_k<<<pg, pb, 0, stream>>>(p1, rowptr, col, wgt, p2, N);
    {
        GemmArgs a{cb, p1, p2, p2, 3, 256, Wt_conv0, conv0_b, nullptr,
                   hb, hb, hb, hb, HDIM, 256, N_pad, sh, 256, N};
        gemm(stream, a, GY, true);
    }

    for (int l = 0; l < 3; ++l) {
        float* shl = sh + l * 512;
        float* sml = sm + l * 2048;

        // zb(e1) = leaky(bn(hb))
        apply_bn_k<<<dim3(1024), dim3(256), 0, stream>>>(hb, shl, norm_g + l * 256,
                                                         norm_b + l * 256, e1, N, invn);

        // conv: cb = [zb | A.zb | A^2.zb] @ Wl + b
        spmm_pull_k<<<pg, pb, 0, stream>>>(e1, rowptr, col, wgt, p1, N);
        spmm_pull_k<<<pg, pb, 0, stream>>>(p1, rowptr, col, wgt, p2, N);
        {
            GemmArgs a{e1, p1, p2, p2, 3, 256, Wt_conv + (size_t)l * 196608,
                       conv_b + l * 256, nullptr, cb, cb, cb, cb, HDIM, 256, N_pad,
                       nullptr, 0, 0};
            gemm(stream, a, GY, true);
        }

        // W1: {p1,p2,e1,e2} = cb @ W1 + b1 ; stats -> sm[l]
        {
            GemmArgs a{cb, cb, cb, cb, 1, 256, Wt_mlp1 + (size_t)l * 262144,
                       mlp_b1 + (size_t)l * 1024, nullptr, p1, p2, e1, e2, HDIM, 1024,
                       N_pad, sml, 1024, N};
            gemm(stream, a, GY, true);
        }

        // hidden = leaky(bn(hidden)) in-place
        apply_bn4_k<<<dim3(2048), dim3(256), 0, stream>>>(p1, p2, e1, e2, sml,
                                                          mlp_g + (size_t)l * 1024,
                                                          mlp_bb + (size_t)l * 1024, N, invn);

        // W2: hb += hidden @ W2 + b2 ; stats -> sh[l+1]
        {
            GemmArgs a{p1, p2, e1, e2, 4, 256, Wt_mlp2 + (size_t)l * 262144,
                       mlp_b2 + l * 256, hb, hb, hb, hb, hb, HDIM, 256, N_pad,
                       sh + (l + 1) * 512, 256, N};
            gemm(stream, a, GY, true);
        }
    }

    // ---- out = hb @ W_out + b_out (f32) ----
    {
        GemmArgs a{hb, hb, hb, hb, 1, 256, Wt_out, b_out, nullptr,
                   d_out, d_out, d_out, d_out, 128, 128, N, nullptr, 0, 0};
        gemm(stream, a, GY, false);
    }
}

// Round 8
// 2140.331 us; speedup vs baseline: 1.1795x; 1.1795x over previous
//
#include <hip/hip_runtime.h>

#define HDIM 256
#define EPSV 1e-5f
#define SLOPEV 0.01f

typedef __bf16 bf16;
typedef bf16  bf16x8 __attribute__((ext_vector_type(8)));
typedef bf16  bf16x4 __attribute__((ext_vector_type(4)));
typedef float f32x4  __attribute__((ext_vector_type(4)));

#define GLD16(g, l) __builtin_amdgcn_global_load_lds( \
    (const __attribute__((address_space(1))) void*)(g), \
    (__attribute__((address_space(3))) void*)(l), 16, 0, 0)

// ================= MFMA GEMM =================
// out = concat_k(A0..A_{nseg-1}) * Wt^T + bias (+addb residual).
// Coalesced bf16 epilogue via LDS staging. Optional per-rowblock column
// partial sums (NO atomics): part[by][colg] sum, part[GY+by][colg] sumsq.
template<bool STORE_BF16>
__global__ __launch_bounds__(256)
void gemm_bt_k(const bf16* A0, const bf16* A1, const bf16* A2, const bf16* A3,
               int nseg, int segK,
               const bf16* __restrict__ Wt,
               const float* __restrict__ bias, const bf16* __restrict__ addb,
               void* out0, void* out1, void* out2, void* out3, int ldo,
               int n_store, float* part, int n_stats)
{
    __shared__ char smem[17408];
    bf16* As = (bf16*)smem;              // [128][32] bf16, 8 KB
    bf16* Bs = (bf16*)(smem + 8192);     // [128][32] bf16, 8 KB

    const int tid = threadIdx.x;
    const int wave = tid >> 6, lane = tid & 63;
    const int quad = lane >> 4, l16 = lane & 15;
    const int waveM = (wave >> 1) * 64, waveN = (wave & 1) * 64;
    const int bm = blockIdx.y * 128, bn = blockIdx.x * 128;
    const int K = nseg * segK;

    const bf16* segs[4] = {A0, A1, A2, A3};
    char* lA0 = (char*)As + wave * 1024;
    char* lA1 = (char*)As + 4096 + wave * 1024;
    char* lB0 = (char*)Bs + wave * 1024;
    char* lB1 = (char*)Bs + 4096 + wave * 1024;
    const bf16* pa = As + (waveM + l16) * 32 + quad * 8;
    const bf16* pb = Bs + (waveN + l16) * 32 + quad * 8;

    f32x4 acc[4][4] = {};

    for (int s = 0; s < nseg; ++s) {
        const bf16* A = segs[s];
        const bf16* gA0 = A + (size_t)(bm + (tid >> 2)) * segK + (tid & 3) * 8;
        const bf16* gA1 = A + (size_t)(bm + 64 + (tid >> 2)) * segK + (tid & 3) * 8;
        const bf16* gB0 = Wt + (size_t)(bn + (tid >> 2)) * K + s * segK + (tid & 3) * 8;
        const bf16* gB1 = Wt + (size_t)(bn + 64 + (tid >> 2)) * K + s * segK + (tid & 3) * 8;
        for (int kt = 0; kt < segK; kt += 32) {
            GLD16(gA0, lA0); GLD16(gA1, lA1);
            GLD16(gB0, lB0); GLD16(gB1, lB1);
            gA0 += 32; gA1 += 32; gB0 += 32; gB1 += 32;
            __syncthreads();

            bf16x8 a0 = *(const bf16x8*)(pa);
            bf16x8 a1 = *(const bf16x8*)(pa + 16 * 32);
            bf16x8 a2 = *(const bf16x8*)(pa + 32 * 32);
            bf16x8 a3 = *(const bf16x8*)(pa + 48 * 32);
            bf16x8 b0 = *(const bf16x8*)(pb);
            bf16x8 b1 = *(const bf16x8*)(pb + 16 * 32);
            bf16x8 b2 = *(const bf16x8*)(pb + 32 * 32);
            bf16x8 b3 = *(const bf16x8*)(pb + 48 * 32);

            acc[0][0] = __builtin_amdgcn_mfma_f32_16x16x32_bf16(a0, b0, acc[0][0], 0, 0, 0);
            acc[0][1] = __builtin_amdgcn_mfma_f32_16x16x32_bf16(a0, b1, acc[0][1], 0, 0, 0);
            acc[0][2] = __builtin_amdgcn_mfma_f32_16x16x32_bf16(a0, b2, acc[0][2], 0, 0, 0);
            acc[0][3] = __builtin_amdgcn_mfma_f32_16x16x32_bf16(a0, b3, acc[0][3], 0, 0, 0);
            acc[1][0] = __builtin_amdgcn_mfma_f32_16x16x32_bf16(a1, b0, acc[1][0], 0, 0, 0);
            acc[1][1] = __builtin_amdgcn_mfma_f32_16x16x32_bf16(a1, b1, acc[1][1], 0, 0, 0);
            acc[1][2] = __builtin_amdgcn_mfma_f32_16x16x32_bf16(a1, b2, acc[1][2], 0, 0, 0);
            acc[1][3] = __builtin_amdgcn_mfma_f32_16x16x32_bf16(a1, b3, acc[1][3], 0, 0, 0);
            acc[2][0] = __builtin_amdgcn_mfma_f32_16x16x32_bf16(a2, b0, acc[2][0], 0, 0, 0);
            acc[2][1] = __builtin_amdgcn_mfma_f32_16x16x32_bf16(a2, b1, acc[2][1], 0, 0, 0);
            acc[2][2] = __builtin_amdgcn_mfma_f32_16x16x32_bf16(a2, b2, acc[2][2], 0, 0, 0);
            acc[2][3] = __builtin_amdgcn_mfma_f32_16x16x32_bf16(a2, b3, acc[2][3], 0, 0, 0);
            acc[3][0] = __builtin_amdgcn_mfma_f32_16x16x32_bf16(a3, b0, acc[3][0], 0, 0, 0);
            acc[3][1] = __builtin_amdgcn_mfma_f32_16x16x32_bf16(a3, b1, acc[3][1], 0, 0, 0);
            acc[3][2] = __builtin_amdgcn_mfma_f32_16x16x32_bf16(a3, b2, acc[3][2], 0, 0, 0);
            acc[3][3] = __builtin_amdgcn_mfma_f32_16x16x32_bf16(a3, b3, acc[3][3], 0, 0, 0);
            __syncthreads();
        }
    }

    float bv[4];
#pragma unroll
    for (int j = 0; j < 4; ++j)
        bv[j] = bias ? bias[bn + waveN + j * 16 + l16] : 0.f;
#pragma unroll
    for (int i = 0; i < 4; ++i)
#pragma unroll
        for (int j = 0; j < 4; ++j)
#pragma unroll
            for (int r = 0; r < 4; ++r)
                acc[i][j][r] += bv[j];

    void* outs[4] = {out0, out1, out2, out3};

    if (STORE_BF16) {
        // per-wave 32x64 staging tile, row stride 68 bf16
        char* stg = smem + wave * 4352;
        float s8[8] = {}, q8[8] = {};
        const int rsel = lane >> 3, csel = lane & 7;
#pragma unroll
        for (int ih = 0; ih < 2; ++ih) {
            __syncthreads();
#pragma unroll
            for (int iw = 0; iw < 2; ++iw) {
                int i = ih * 2 + iw;
#pragma unroll
                for (int j = 0; j < 4; ++j)
#pragma unroll
                    for (int r = 0; r < 4; ++r)
                        *(bf16*)(stg + ((iw * 16 + quad * 4 + r) * 68 + j * 16 + l16) * 2)
                            = (bf16)acc[i][j][r];
            }
            __syncthreads();
#pragma unroll
            for (int rr = 0; rr < 4; ++rr) {
                int rl = rsel + rr * 8;
                bf16x4 lo = *(const bf16x4*)(stg + (rl * 68 + csel * 8) * 2);
                bf16x4 hi = *(const bf16x4*)(stg + (rl * 68 + csel * 8 + 4) * 2);
                int rowg = bm + waveM + ih * 32 + rl;
                int colg = bn + waveN + csel * 8;
                int cseg = colg >> 8, cloc = colg & 255;
                size_t idx = (size_t)rowg * ldo + cloc;
                float f[8];
#pragma unroll
                for (int u = 0; u < 4; ++u) { f[u] = (float)lo[u]; f[4 + u] = (float)hi[u]; }
                if (addb) {
                    bf16x8 o = *(const bf16x8*)(addb + idx);
#pragma unroll
                    for (int u = 0; u < 8; ++u) f[u] += (float)o[u];
                }
                bf16x8 w;
#pragma unroll
                for (int u = 0; u < 8; ++u) w[u] = (bf16)f[u];
                if (rowg < n_store) *(bf16x8*)((bf16*)outs[cseg] + idx) = w;
                if (part && rowg < n_stats) {
#pragma unroll
                    for (int u = 0; u < 8; ++u) { s8[u] += f[u]; q8[u] += f[u] * f[u]; }
                }
            }
        }
        if (part) {
            // reduce across rsel (rows) within wave
#pragma unroll
            for (int m = 8; m <= 32; m <<= 1)
#pragma unroll
                for (int u = 0; u < 8; ++u) {
                    s8[u] += __shfl_xor(s8[u], m, 64);
                    q8[u] += __shfl_xor(q8[u], m, 64);
                }
            __syncthreads();
            float* Ls = (float*)smem;          // [4][64]
            float* Lq = Ls + 256;              // [4][64]
            if (rsel == 0) {
#pragma unroll
                for (int u = 0; u < 8; ++u) {
                    Ls[wave * 64 + csel * 8 + u] = s8[u];
                    Lq[wave * 64 + csel * 8 + u] = q8[u];
                }
            }
            __syncthreads();
            if (tid < 128) {
                int hi = tid >> 6, c6 = tid & 63;        // hi=0: waves 0&2, hi=1: 1&3
                float s = Ls[hi * 64 + c6] + Ls[(hi + 2) * 64 + c6];
                float q = Lq[hi * 64 + c6] + Lq[(hi + 2) * 64 + c6];
                int Mtot = gridDim.x * 128;
                int colg = bn + tid;
                part[(size_t)blockIdx.y * Mtot + colg] = s;
                part[(size_t)(gridDim.y + blockIdx.y) * Mtot + colg] = q;
            }
        }
    } else {
#pragma unroll
        for (int i = 0; i < 4; ++i)
#pragma unroll
            for (int j = 0; j < 4; ++j) {
                int colg = bn + waveN + j * 16 + l16;
                int cseg = colg >> 8, cloc = colg & 255;
#pragma unroll
                for (int r = 0; r < 4; ++r) {
                    int rowg = bm + waveM + i * 16 + quad * 4 + r;
                    if (rowg < n_store)
                        ((float*)outs[cseg])[(size_t)rowg * ldo + cloc] = acc[i][j][r];
                }
            }
    }
}

// ================= finalize: reduce partials -> BN coeffs (a, b') =================
__global__ __launch_bounds__(256)
void finalize_k(const float* __restrict__ part, int GY, int M,
                const float* __restrict__ g, const float* __restrict__ bb,
                float* __restrict__ coef, float invn)
{
    int c = blockIdx.x * 256 + threadIdx.x;
    if (c >= M) return;
    float s = 0.f, q = 0.f;
    const float* ps = part + c;
    const float* pq = part + (size_t)GY * M + c;
    for (int i = 0; i < GY; ++i) {
        s += ps[(size_t)i * M];
        q += pq[(size_t)i * M];
    }
    float mean = s * invn;
    float var  = q * invn - mean * mean;
    float a = g[c] * rsqrtf(var + EPSV);
    coef[c]     = a;
    coef[M + c] = bb[c] - mean * a;
}

// ================= transpose+convert =================
__global__ __launch_bounds__(256)
void transpose_cvt_k(const float* __restrict__ src, bf16* __restrict__ dst,
                     int Kseg, int M, int G)
{
    __shared__ float t[32][33];
    const int z = blockIdx.z;
    src += (size_t)z * Kseg * M;
    const int ldd = G * Kseg;
    dst += (size_t)(z / G) * M * ldd + (size_t)(z % G) * Kseg;
    const int tM = blockIdx.x * 32, tK = blockIdx.y * 32;
    const int tx = threadIdx.x & 31, ty = threadIdx.x >> 5;
#pragma unroll
    for (int r = 0; r < 4; ++r)
        t[ty + r * 8][tx] = src[(size_t)(tK + ty + r * 8) * M + tM + tx];
    __syncthreads();
#pragma unroll
    for (int r = 0; r < 4; ++r)
        dst[(size_t)(tM + ty + r * 8) * ldd + tK + tx] = (bf16)t[tx][ty + r * 8];
}

__global__ __launch_bounds__(256)
void cvt_bf_k(const float* __restrict__ src, bf16* __restrict__ dst, long n4)
{
    long i = (long)blockIdx.x * blockDim.x + threadIdx.x;
    if (i >= n4) return;
    float4 v = ((const float4*)src)[i];
    bf16x4 o; o[0] = (bf16)v.x; o[1] = (bf16)v.y; o[2] = (bf16)v.z; o[3] = (bf16)v.w;
    ((bf16x4*)dst)[i] = o;
}

// ================= CSR build =================
__global__ __launch_bounds__(256)
void deg_k(const int* __restrict__ dst, int* __restrict__ deg, int E)
{
    int e = blockIdx.x * blockDim.x + threadIdx.x;
    if (e < E) atomicAdd(&deg[dst[e]], 1);
}

__global__ __launch_bounds__(1024)
void scan_k(int* __restrict__ deg_wp, int* __restrict__ rowptr, int N)
{
    __shared__ int s[1024];
    const int tid = threadIdx.x;
    if (tid == 0) rowptr[0] = 0;
    int running = 0;
    for (int base = 0; base < N; base += 1024) {
        int i = base + tid;
        int x = (i < N) ? deg_wp[i] : 0;
        s[tid] = x;
        __syncthreads();
        for (int off = 1; off < 1024; off <<= 1) {
            int t = (tid >= off) ? s[tid - off] : 0;
            __syncthreads();
            s[tid] += t;
            __syncthreads();
        }
        if (i < N) {
            rowptr[i + 1] = s[tid] + running;
            deg_wp[i]     = s[tid] + running - x;
        }
        running += s[1023];
        __syncthreads();
    }
}

__global__ __launch_bounds__(256)
void reorder_k(const int* __restrict__ src, const int* __restrict__ dst,
               const float* __restrict__ ew, int* __restrict__ wp,
               int* __restrict__ col, float* __restrict__ wgt, int E)
{
    int e = blockIdx.x * blockDim.x + threadIdx.x;
    if (e >= E) return;
    int d = dst[e];
    int pos = atomicAdd(&wp[d], 1);
    col[pos] = src[e];
    wgt[pos] = ew[e];
}

// ================= pull SpMM: half-wave (32 lanes x bf16x8) per node =================
__global__ __launch_bounds__(256)
void spmm_pull_k(const bf16* __restrict__ P, const int* __restrict__ rowptr,
                 const int* __restrict__ col, const float* __restrict__ wgt,
                 bf16* __restrict__ Q, int N)
{
    int node = blockIdx.x * 8 + (threadIdx.x >> 5);
    int l = threadIdx.x & 31;
    if (node >= N) return;
    int e = rowptr[node], end = rowptr[node + 1];
    float acc[8] = {};
    for (; e + 1 < end; e += 2) {
        int   s0 = col[e], s1 = col[e + 1];
        float w0 = wgt[e], w1 = wgt[e + 1];
        bf16x8 v0 = *(const bf16x8*)(P + (size_t)s0 * HDIM + l * 8);
        bf16x8 v1 = *(const bf16x8*)(P + (size_t)s1 * HDIM + l * 8);
#pragma unroll
        for (int u = 0; u < 8; ++u)
            acc[u] += (float)v0[u] * w0 + (float)v1[u] * w1;
    }
    if (e < end) {
        int s0 = col[e]; float w0 = wgt[e];
        bf16x8 v0 = *(const bf16x8*)(P + (size_t)s0 * HDIM + l * 8);
#pragma unroll
        for (int u = 0; u < 8; ++u) acc[u] += (float)v0[u] * w0;
    }
    bf16x8 o;
#pragma unroll
    for (int u = 0; u < 8; ++u) o[u] = (bf16)acc[u];
    *(bf16x8*)(Q + (size_t)node * HDIM + l * 8) = o;
}

// ================= BN apply (coeffs precomputed) =================
__global__ __launch_bounds__(256)
void apply_bn_k(const bf16* __restrict__ X, const float* __restrict__ coef,
                bf16* __restrict__ Y, int n)
{
    __shared__ float aL[256], bL[256];
    const int tid = threadIdx.x;
    aL[tid] = coef[tid]; bL[tid] = coef[256 + tid];
    __syncthreads();
    long n4 = (long)n * 64;
    for (long i = (long)blockIdx.x * 256 + tid; i < n4; i += (long)gridDim.x * 256) {
        bf16x4 v = ((const bf16x4*)X)[i];
        int c4 = (int)(i & 63) * 4;
        float r0 = fmaf((float)v[0], aL[c4 + 0], bL[c4 + 0]); r0 = r0 > 0.f ? r0 : SLOPEV * r0;
        float r1 = fmaf((float)v[1], aL[c4 + 1], bL[c4 + 1]); r1 = r1 > 0.f ? r1 : SLOPEV * r1;
        float r2 = fmaf((float)v[2], aL[c4 + 2], bL[c4 + 2]); r2 = r2 > 0.f ? r2 : SLOPEV * r2;
        float r3 = fmaf((float)v[3], aL[c4 + 3], bL[c4 + 3]); r3 = r3 > 0.f ? r3 : SLOPEV * r3;
        bf16x4 o; o[0] = (bf16)r0; o[1] = (bf16)r1; o[2] = (bf16)r2; o[3] = (bf16)r3;
        ((bf16x4*)Y)[i] = o;
    }
}

__global__ __launch_bounds__(256)
void apply_bn4_k(bf16* X0, bf16* X1, bf16* X2, bf16* X3,
                 const float* __restrict__ coef, int n)
{
    __shared__ float aL[1024], bL[1024];
    const int tid = threadIdx.x;
#pragma unroll
    for (int q = 0; q < 4; ++q) {
        int c = q * 256 + tid;
        aL[c] = coef[c]; bL[c] = coef[1024 + c];
    }
    __syncthreads();
    bf16* Xs[4] = {X0, X1, X2, X3};
    long per = (long)n * 64;
    long stride = (long)gridDim.x * 256;
    for (int q = 0; q < 4; ++q) {
        bf16* X = Xs[q];
        int cbase = q * 256;
        for (long i = (long)blockIdx.x * 256 + tid; i < per; i += stride) {
            bf16x4 v = ((const bf16x4*)X)[i];
            int c4 = cbase + (int)(i & 63) * 4;
            float r0 = fmaf((float)v[0], aL[c4 + 0], bL[c4 + 0]); r0 = r0 > 0.f ? r0 : SLOPEV * r0;
            float r1 = fmaf((float)v[1], aL[c4 + 1], bL[c4 + 1]); r1 = r1 > 0.f ? r1 : SLOPEV * r1;
            float r2 = fmaf((float)v[2], aL[c4 + 2], bL[c4 + 2]); r2 = r2 > 0.f ? r2 : SLOPEV * r2;
            float r3 = fmaf((float)v[3], aL[c4 + 3], bL[c4 + 3]); r3 = r3 > 0.f ? r3 : SLOPEV * r3;
            bf16x4 o; o[0] = (bf16)r0; o[1] = (bf16)r1; o[2] = (bf16)r2; o[3] = (bf16)r3;
            ((bf16x4*)X)[i] = o;
        }
    }
}

// ================= host =================
struct GemmArgs {
    const bf16 *A0, *A1, *A2, *A3; int nseg, segK;
    const bf16* Wt; const float* bias; const bf16* addb;
    void *o0, *o1, *o2, *o3; int ldo, M, n_store;
    float* part; int n_stats;
};

static void gemm(hipStream_t st, const GemmArgs& a, int GY, bool store_bf16)
{
    dim3 g(a.M / 128, GY), b(256);
    if (store_bf16)
        gemm_bt_k<true><<<g, b, 0, st>>>(a.A0, a.A1, a.A2, a.A3, a.nseg, a.segK,
            a.Wt, a.bias, a.addb, a.o0, a.o1, a.o2, a.o3, a.ldo, a.n_store,
            a.part, a.n_stats);
    else
        gemm_bt_k<false><<<g, b, 0, st>>>(a.A0, a.A1, a.A2, a.A3, a.nseg, a.segK,
            a.Wt, a.bias, a.addb, a.o0, a.o1, a.o2, a.o3, a.ldo, a.n_store,
            a.part, a.n_stats);
}

extern "C" void kernel_launch(void* const* d_in, const int* in_sizes, int n_in,
                              void* d_out, int out_size, void* d_ws, size_t ws_size,
                              hipStream_t stream)
{
    const float* x       = (const float*)d_in[0];
    const int*   ei      = (const int*)d_in[1];
    const float* ew      = (const float*)d_in[2];
    const float* W_emb   = (const float*)d_in[3];
    const float* b_emb   = (const float*)d_in[4];
    const float* conv0_W = (const float*)d_in[5];
    const float* conv0_b = (const float*)d_in[6];
    const float* norm_g  = (const float*)d_in[7];
    const float* norm_b  = (const float*)d_in[8];
    const float* conv_W  = (const float*)d_in[9];
    const float* conv_b  = (const float*)d_in[10];
    const float* mlp_W1  = (const float*)d_in[11];
    const float* mlp_b1  = (const float*)d_in[12];
    const float* mlp_g   = (const float*)d_in[13];
    const float* mlp_bb  = (const float*)d_in[14];
    const float* mlp_W2  = (const float*)d_in[15];
    const float* mlp_b2  = (const float*)d_in[16];
    const float* W_out   = (const float*)d_in[17];
    const float* b_out   = (const float*)d_in[18];

    const int N = in_sizes[0] / 128;          // 50000
    const int E = in_sizes[2];                // 800000
    const int* srcI = ei;
    const int* dstI = ei + E;
    const int N_pad = ((N + 127) / 128) * 128;
    const int GY = N_pad / 128;

    const size_t NHp = (size_t)N_pad * HDIM;
    bf16* xb = (bf16*)d_ws;                      // N_pad x 128
    bf16* hb = xb + (size_t)N_pad * 128;
    bf16* cb = hb + NHp;
    bf16* p1 = cb + NHp;
    bf16* p2 = p1 + NHp;
    bf16* e1 = p2 + NHp;                         // doubles as zb
    bf16* e2 = e1 + NHp;
    bf16* wa = e2 + NHp;                         // weight arena
    bf16* Wt_emb   = wa;
    bf16* Wt_conv0 = wa + 32768;
    bf16* Wt_conv  = wa + 229376;
    bf16* Wt_mlp1  = wa + 819200;
    bf16* Wt_mlp2  = wa + 1605632;
    bf16* Wt_out   = wa + 2392064;
    float* cf_h   = (float*)(wa + 2424832);      // 512 coeffs (h BN)
    float* cf_m   = cf_h + 512;                  // 2048 coeffs (mlp BN)
    float* partb  = cf_m + 2048;                 // 2*GY*1024 floats max (3.2 MB)
    int*   rowptr = (int*)(partb + 2 * (size_t)GY * 1024);
    int*   wp     = rowptr + (N + 1);
    int*   col    = wp + N;
    float* wgt    = (float*)(col + E);

    const float invn = 1.0f / (float)N;
    dim3 pg((N + 7) / 8), pb(256);

    // ---- CSR build ----
    hipMemsetAsync(wp, 0, (size_t)N * 4, stream);
    deg_k<<<dim3((E + 255) / 256), dim3(256), 0, stream>>>(dstI, wp, E);
    scan_k<<<dim3(1), dim3(1024), 0, stream>>>(wp, rowptr, N);
    reorder_k<<<dim3((E + 255) / 256), dim3(256), 0, stream>>>(srcI, dstI, ew, wp, col, wgt, E);

    // ---- convert inputs/weights ----
    cvt_bf_k<<<dim3((N * 32 + 255) / 256), dim3(256), 0, stream>>>(x, xb, (long)N * 32);
    transpose_cvt_k<<<dim3(8, 4, 1), dim3(256), 0, stream>>>(W_emb, Wt_emb, 128, 256, 1);
    transpose_cvt_k<<<dim3(8, 8, 3), dim3(256), 0, stream>>>(conv0_W, Wt_conv0, 256, 256, 3);
    transpose_cvt_k<<<dim3(8, 8, 9), dim3(256), 0, stream>>>(conv_W, Wt_conv, 256, 256, 3);
    transpose_cvt_k<<<dim3(32, 8, 3), dim3(256), 0, stream>>>(mlp_W1, Wt_mlp1, 256, 1024, 1);
    transpose_cvt_k<<<dim3(8, 32, 3), dim3(256), 0, stream>>>(mlp_W2, Wt_mlp2, 1024, 256, 1);
    transpose_cvt_k<<<dim3(4, 8, 1), dim3(256), 0, stream>>>(W_out, Wt_out, 256, 128, 1);

    // ---- embed: cb = bf16(x @ W_emb + b_emb) ----
    {
        GemmArgs a{xb, xb, xb, xb, 1, 128, Wt_emb, b_emb, nullptr,
                   cb, cb, cb, cb, HDIM, 256, N_pad, nullptr, 0};
        gemm(stream, a, GY, true);
    }

    // ---- conv0: hb = [cb | A.cb | A^2.cb] @ Wt_conv0 + b ; partials -> finalize cf_h ----
    spmm_pull_k<<<pg, pb, 0, stream>>>(cb, rowptr, col, wgt, p1, N);
    spmm_pull_k<<<pg, pb, 0, stream>>>(p1, rowptr, col, wgt, p2, N);
    {
        GemmArgs a{cb, p1, p2, p2, 3, 256, Wt_conv0, conv0_b, nullptr,
                   hb, hb, hb, hb, HDIM, 256, N_pad, partb, N};
        gemm(stream, a, GY, true);
    }
    finalize_k<<<dim3(1), dim3(256), 0, stream>>>(partb, GY, 256, norm_g, norm_b, cf_h, invn);

    for (int l = 0; l < 3; ++l) {
        // zb(e1) = leaky(bn(hb)) using precomputed coeffs
        apply_bn_k<<<dim3(1024), dim3(256), 0, stream>>>(hb, cf_h, e1, N);

        // conv: cb = [zb | A.zb | A^2.zb] @ Wl + b
        spmm_pull_k<<<pg, pb, 0, stream>>>(e1, rowptr, col, wgt, p1, N);
        spmm_pull_k<<<pg, pb, 0, stream>>>(p1, rowptr, col, wgt, p2, N);
        {
            GemmArgs a{e1, p1, p2, p2, 3, 256, Wt_conv + (size_t)l * 196608,
                       conv_b + l * 256, nullptr, cb, cb, cb, cb, HDIM, 256, N_pad,
                       nullptr, 0};
            gemm(stream, a, GY, true);
        }

        // W1: {p1,p2,e1,e2} = cb @ W1 + b1 ; partials -> finalize cf_m
        {
            GemmArgs a{cb, cb, cb, cb, 1, 256, Wt_mlp1 + (size_t)l * 262144,
                       mlp_b1 + (size_t)l * 1024, nullptr, p1, p2, e1, e2, HDIM, 1024,
                       N_pad, partb, N};
            gemm(stream, a, GY, true);
        }
        finalize_k<<<dim3(4), dim3(256), 0, stream>>>(partb, GY, 1024,
                                                      mlp_g + (size_t)l * 1024,
                                                      mlp_bb + (size_t)l * 1024, cf_m, invn);

        // hidden = leaky(bn(hidden)) in-place
        apply_bn4_k<<<dim3(2048), dim3(256), 0, stream>>>(p1, p2, e1, e2, cf_m, N);

        // W2: hb += hidden @ W2 + b2 ; partials for next layer's h-BN (if any)
        {
            GemmArgs a{p1, p2, e1, e2, 4, 256, Wt_mlp2 + (size_t)l * 262144,
                       mlp_b2 + l * 256, hb, hb, hb, hb, hb, HDIM, 256, N_pad,
                       (l < 2) ? partb : nullptr, N};
            gemm(stream, a, GY, true);
        }
        if (l < 2)
            finalize_k<<<dim3(1), dim3(256), 0, stream>>>(partb, GY, 256,
                                                          norm_g + (l + 1) * 256,
                                                          norm_b + (l + 1) * 256, cf_h, invn);
    }

    // ---- out = hb @ W_out + b_out (f32) ----
    {
        GemmArgs a{hb, hb, hb, hb, 1, 256, Wt_out, b_out, nullptr,
                   d_out, d_out, d_out, d_out, 128, 128, N, nullptr, 0};
        gemm(stream, a, GY, false);
    }
}

// Round 9
// 1543.057 us; speedup vs baseline: 1.6361x; 1.3871x over previous
//
#include <hip/hip_runtime.h>

#define HDIM 256
#define EPSV 1e-5f
#define SLOPEV 0.01f

typedef __bf16 bf16;
typedef bf16  bf16x8 __attribute__((ext_vector_type(8)));
typedef bf16  bf16x4 __attribute__((ext_vector_type(4)));
typedef float f32x4  __attribute__((ext_vector_type(4)));

#define GLD16(g, l) __builtin_amdgcn_global_load_lds( \
    (const __attribute__((address_space(1))) void*)(g), \
    (__attribute__((address_space(3))) void*)(l), 16, 0, 0)

// ================= MFMA GEMM =================
// out = concat_k(A0..A_{nseg-1}) * Wt^T + bias (+addb residual).
// Coalesced bf16 epilogue via LDS staging. Optional per-rowblock column
// partial sums (NO atomics): part[by][colg] sum, part[GY+by][colg] sumsq.
template<bool STORE_BF16>
__global__ __launch_bounds__(256)
void gemm_bt_k(const bf16* A0, const bf16* A1, const bf16* A2, const bf16* A3,
               int nseg, int segK,
               const bf16* __restrict__ Wt,
               const float* __restrict__ bias, const bf16* __restrict__ addb,
               void* out0, void* out1, void* out2, void* out3, int ldo,
               int n_store, float* part, int n_stats)
{
    __shared__ char smem[17408];
    bf16* As = (bf16*)smem;              // [128][32] bf16, 8 KB
    bf16* Bs = (bf16*)(smem + 8192);     // [128][32] bf16, 8 KB

    const int tid = threadIdx.x;
    const int wave = tid >> 6, lane = tid & 63;
    const int quad = lane >> 4, l16 = lane & 15;
    const int waveM = (wave >> 1) * 64, waveN = (wave & 1) * 64;
    const int bm = blockIdx.y * 128, bn = blockIdx.x * 128;
    const int K = nseg * segK;

    const bf16* segs[4] = {A0, A1, A2, A3};
    char* lA0 = (char*)As + wave * 1024;
    char* lA1 = (char*)As + 4096 + wave * 1024;
    char* lB0 = (char*)Bs + wave * 1024;
    char* lB1 = (char*)Bs + 4096 + wave * 1024;
    const bf16* pa = As + (waveM + l16) * 32 + quad * 8;
    const bf16* pb = Bs + (waveN + l16) * 32 + quad * 8;

    f32x4 acc[4][4] = {};

    for (int s = 0; s < nseg; ++s) {
        const bf16* A = segs[s];
        const bf16* gA0 = A + (size_t)(bm + (tid >> 2)) * segK + (tid & 3) * 8;
        const bf16* gA1 = A + (size_t)(bm + 64 + (tid >> 2)) * segK + (tid & 3) * 8;
        const bf16* gB0 = Wt + (size_t)(bn + (tid >> 2)) * K + s * segK + (tid & 3) * 8;
        const bf16* gB1 = Wt + (size_t)(bn + 64 + (tid >> 2)) * K + s * segK + (tid & 3) * 8;
        for (int kt = 0; kt < segK; kt += 32) {
            GLD16(gA0, lA0); GLD16(gA1, lA1);
            GLD16(gB0, lB0); GLD16(gB1, lB1);
            gA0 += 32; gA1 += 32; gB0 += 32; gB1 += 32;
            __syncthreads();

            bf16x8 a0 = *(const bf16x8*)(pa);
            bf16x8 a1 = *(const bf16x8*)(pa + 16 * 32);
            bf16x8 a2 = *(const bf16x8*)(pa + 32 * 32);
            bf16x8 a3 = *(const bf16x8*)(pa + 48 * 32);
            bf16x8 b0 = *(const bf16x8*)(pb);
            bf16x8 b1 = *(const bf16x8*)(pb + 16 * 32);
            bf16x8 b2 = *(const bf16x8*)(pb + 32 * 32);
            bf16x8 b3 = *(const bf16x8*)(pb + 48 * 32);

            acc[0][0] = __builtin_amdgcn_mfma_f32_16x16x32_bf16(a0, b0, acc[0][0], 0, 0, 0);
            acc[0][1] = __builtin_amdgcn_mfma_f32_16x16x32_bf16(a0, b1, acc[0][1], 0, 0, 0);
            acc[0][2] = __builtin_amdgcn_mfma_f32_16x16x32_bf16(a0, b2, acc[0][2], 0, 0, 0);
            acc[0][3] = __builtin_amdgcn_mfma_f32_16x16x32_bf16(a0, b3, acc[0][3], 0, 0, 0);
            acc[1][0] = __builtin_amdgcn_mfma_f32_16x16x32_bf16(a1, b0, acc[1][0], 0, 0, 0);
            acc[1][1] = __builtin_amdgcn_mfma_f32_16x16x32_bf16(a1, b1, acc[1][1], 0, 0, 0);
            acc[1][2] = __builtin_amdgcn_mfma_f32_16x16x32_bf16(a1, b2, acc[1][2], 0, 0, 0);
            acc[1][3] = __builtin_amdgcn_mfma_f32_16x16x32_bf16(a1, b3, acc[1][3], 0, 0, 0);
            acc[2][0] = __builtin_amdgcn_mfma_f32_16x16x32_bf16(a2, b0, acc[2][0], 0, 0, 0);
            acc[2][1] = __builtin_amdgcn_mfma_f32_16x16x32_bf16(a2, b1, acc[2][1], 0, 0, 0);
            acc[2][2] = __builtin_amdgcn_mfma_f32_16x16x32_bf16(a2, b2, acc[2][2], 0, 0, 0);
            acc[2][3] = __builtin_amdgcn_mfma_f32_16x16x32_bf16(a2, b3, acc[2][3], 0, 0, 0);
            acc[3][0] = __builtin_amdgcn_mfma_f32_16x16x32_bf16(a3, b0, acc[3][0], 0, 0, 0);
            acc[3][1] = __builtin_amdgcn_mfma_f32_16x16x32_bf16(a3, b1, acc[3][1], 0, 0, 0);
            acc[3][2] = __builtin_amdgcn_mfma_f32_16x16x32_bf16(a3, b2, acc[3][2], 0, 0, 0);
            acc[3][3] = __builtin_amdgcn_mfma_f32_16x16x32_bf16(a3, b3, acc[3][3], 0, 0, 0);
            __syncthreads();
        }
    }

    float bv[4];
#pragma unroll
    for (int j = 0; j < 4; ++j)
        bv[j] = bias ? bias[bn + waveN + j * 16 + l16] : 0.f;
#pragma unroll
    for (int i = 0; i < 4; ++i)
#pragma unroll
        for (int j = 0; j < 4; ++j)
#pragma unroll
            for (int r = 0; r < 4; ++r)
                acc[i][j][r] += bv[j];

    void* outs[4] = {out0, out1, out2, out3};

    if (STORE_BF16) {
        // per-wave 32x64 staging tile, row stride 68 bf16
        char* stg = smem + wave * 4352;
        float s8[8] = {}, q8[8] = {};
        const int rsel = lane >> 3, csel = lane & 7;
#pragma unroll
        for (int ih = 0; ih < 2; ++ih) {
            __syncthreads();
#pragma unroll
            for (int iw = 0; iw < 2; ++iw) {
                int i = ih * 2 + iw;
#pragma unroll
                for (int j = 0; j < 4; ++j)
#pragma unroll
                    for (int r = 0; r < 4; ++r)
                        *(bf16*)(stg + ((iw * 16 + quad * 4 + r) * 68 + j * 16 + l16) * 2)
                            = (bf16)acc[i][j][r];
            }
            __syncthreads();
#pragma unroll
            for (int rr = 0; rr < 4; ++rr) {
                int rl = rsel + rr * 8;
                bf16x4 lo = *(const bf16x4*)(stg + (rl * 68 + csel * 8) * 2);
                bf16x4 hi = *(const bf16x4*)(stg + (rl * 68 + csel * 8 + 4) * 2);
                int rowg = bm + waveM + ih * 32 + rl;
                int colg = bn + waveN + csel * 8;
                int cseg = colg >> 8, cloc = colg & 255;
                size_t idx = (size_t)rowg * ldo + cloc;
                float f[8];
#pragma unroll
                for (int u = 0; u < 4; ++u) { f[u] = (float)lo[u]; f[4 + u] = (float)hi[u]; }
                if (addb) {
                    bf16x8 o = *(const bf16x8*)(addb + idx);
#pragma unroll
                    for (int u = 0; u < 8; ++u) f[u] += (float)o[u];
                }
                bf16x8 w;
#pragma unroll
                for (int u = 0; u < 8; ++u) w[u] = (bf16)f[u];
                if (rowg < n_store) *(bf16x8*)((bf16*)outs[cseg] + idx) = w;
                if (part && rowg < n_stats) {
#pragma unroll
                    for (int u = 0; u < 8; ++u) { s8[u] += f[u]; q8[u] += f[u] * f[u]; }
                }
            }
        }
        if (part) {
            // reduce across rsel (rows) within wave
#pragma unroll
            for (int m = 8; m <= 32; m <<= 1)
#pragma unroll
                for (int u = 0; u < 8; ++u) {
                    s8[u] += __shfl_xor(s8[u], m, 64);
                    q8[u] += __shfl_xor(q8[u], m, 64);
                }
            __syncthreads();
            float* Ls = (float*)smem;          // [4][64]
            float* Lq = Ls + 256;              // [4][64]
            if (rsel == 0) {
#pragma unroll
                for (int u = 0; u < 8; ++u) {
                    Ls[wave * 64 + csel * 8 + u] = s8[u];
                    Lq[wave * 64 + csel * 8 + u] = q8[u];
                }
            }
            __syncthreads();
            if (tid < 128) {
                int hi = tid >> 6, c6 = tid & 63;        // hi=0: waves 0&2, hi=1: 1&3
                float s = Ls[hi * 64 + c6] + Ls[(hi + 2) * 64 + c6];
                float q = Lq[hi * 64 + c6] + Lq[(hi + 2) * 64 + c6];
                int Mtot = gridDim.x * 128;
                int colg = bn + tid;
                part[(size_t)blockIdx.y * Mtot + colg] = s;
                part[(size_t)(gridDim.y + blockIdx.y) * Mtot + colg] = q;
            }
        }
    } else {
#pragma unroll
        for (int i = 0; i < 4; ++i)
#pragma unroll
            for (int j = 0; j < 4; ++j) {
                int colg = bn + waveN + j * 16 + l16;
                int cseg = colg >> 8, cloc = colg & 255;
#pragma unroll
                for (int r = 0; r < 4; ++r) {
                    int rowg = bm + waveM + i * 16 + quad * 4 + r;
                    if (rowg < n_store)
                        ((float*)outs[cseg])[(size_t)rowg * ldo + cloc] = acc[i][j][r];
                }
            }
    }
}

// ================= finalize: one block per column, tree reduce =================
__global__ __launch_bounds__(256)
void finalize_k(const float* __restrict__ part, int GY, int M,
                const float* __restrict__ g, const float* __restrict__ bb,
                float* __restrict__ coef, float invn)
{
    const int c = blockIdx.x;
    const int t = threadIdx.x;
    float s = 0.f, q = 0.f;
    const float* ps = part + c;
    const float* pq = part + (size_t)GY * M + c;
    for (int i = t; i < GY; i += 256) {
        s += ps[(size_t)i * M];
        q += pq[(size_t)i * M];
    }
#pragma unroll
    for (int m = 1; m <= 32; m <<= 1) {
        s += __shfl_xor(s, m, 64);
        q += __shfl_xor(q, m, 64);
    }
    __shared__ float Ls[4], Lq[4];
    const int w = t >> 6, l = t & 63;
    if (l == 0) { Ls[w] = s; Lq[w] = q; }
    __syncthreads();
    if (t == 0) {
        s = Ls[0] + Ls[1] + Ls[2] + Ls[3];
        q = Lq[0] + Lq[1] + Lq[2] + Lq[3];
        float mean = s * invn;
        float var  = q * invn - mean * mean;
        float a = g[c] * rsqrtf(var + EPSV);
        coef[c]     = a;
        coef[M + c] = bb[c] - mean * a;
    }
}

// ================= transpose+convert =================
__global__ __launch_bounds__(256)
void transpose_cvt_k(const float* __restrict__ src, bf16* __restrict__ dst,
                     int Kseg, int M, int G)
{
    __shared__ float t[32][33];
    const int z = blockIdx.z;
    src += (size_t)z * Kseg * M;
    const int ldd = G * Kseg;
    dst += (size_t)(z / G) * M * ldd + (size_t)(z % G) * Kseg;
    const int tM = blockIdx.x * 32, tK = blockIdx.y * 32;
    const int tx = threadIdx.x & 31, ty = threadIdx.x >> 5;
#pragma unroll
    for (int r = 0; r < 4; ++r)
        t[ty + r * 8][tx] = src[(size_t)(tK + ty + r * 8) * M + tM + tx];
    __syncthreads();
#pragma unroll
    for (int r = 0; r < 4; ++r)
        dst[(size_t)(tM + ty + r * 8) * ldd + tK + tx] = (bf16)t[tx][ty + r * 8];
}

__global__ __launch_bounds__(256)
void cvt_bf_k(const float* __restrict__ src, bf16* __restrict__ dst, long n4)
{
    long i = (long)blockIdx.x * blockDim.x + threadIdx.x;
    if (i >= n4) return;
    float4 v = ((const float4*)src)[i];
    bf16x4 o; o[0] = (bf16)v.x; o[1] = (bf16)v.y; o[2] = (bf16)v.z; o[3] = (bf16)v.w;
    ((bf16x4*)dst)[i] = o;
}

// ================= CSR build =================
__global__ __launch_bounds__(256)
void deg_k(const int* __restrict__ dst, int* __restrict__ deg, int E)
{
    int e = blockIdx.x * blockDim.x + threadIdx.x;
    if (e < E) atomicAdd(&deg[dst[e]], 1);
}

__global__ __launch_bounds__(1024)
void scan_k(int* __restrict__ deg_wp, int* __restrict__ rowptr, int N)
{
    __shared__ int s[1024];
    const int tid = threadIdx.x;
    if (tid == 0) rowptr[0] = 0;
    int running = 0;
    for (int base = 0; base < N; base += 1024) {
        int i = base + tid;
        int x = (i < N) ? deg_wp[i] : 0;
        s[tid] = x;
        __syncthreads();
        for (int off = 1; off < 1024; off <<= 1) {
            int t = (tid >= off) ? s[tid - off] : 0;
            __syncthreads();
            s[tid] += t;
            __syncthreads();
        }
        if (i < N) {
            rowptr[i + 1] = s[tid] + running;
            deg_wp[i]     = s[tid] + running - x;
        }
        running += s[1023];
        __syncthreads();
    }
}

__global__ __launch_bounds__(256)
void reorder_k(const int* __restrict__ src, const int* __restrict__ dst,
               const float* __restrict__ ew, int* __restrict__ wp,
               int* __restrict__ col, float* __restrict__ wgt, int E)
{
    int e = blockIdx.x * blockDim.x + threadIdx.x;
    if (e >= E) return;
    int d = dst[e];
    int pos = atomicAdd(&wp[d], 1);
    col[pos] = src[e];
    wgt[pos] = ew[e];
}

// ================= pull SpMM: half-wave (32 lanes x bf16x8) per node =================
__global__ __launch_bounds__(256)
void spmm_pull_k(const bf16* __restrict__ P, const int* __restrict__ rowptr,
                 const int* __restrict__ col, const float* __restrict__ wgt,
                 bf16* __restrict__ Q, int N)
{
    int node = blockIdx.x * 8 + (threadIdx.x >> 5);
    int l = threadIdx.x & 31;
    if (node >= N) return;
    int e = rowptr[node], end = rowptr[node + 1];
    float acc[8] = {};
    for (; e + 1 < end; e += 2) {
        int   s0 = col[e], s1 = col[e + 1];
        float w0 = wgt[e], w1 = wgt[e + 1];
        bf16x8 v0 = *(const bf16x8*)(P + (size_t)s0 * HDIM + l * 8);
        bf16x8 v1 = *(const bf16x8*)(P + (size_t)s1 * HDIM + l * 8);
#pragma unroll
        for (int u = 0; u < 8; ++u)
            acc[u] += (float)v0[u] * w0 + (float)v1[u] * w1;
    }
    if (e < end) {
        int s0 = col[e]; float w0 = wgt[e];
        bf16x8 v0 = *(const bf16x8*)(P + (size_t)s0 * HDIM + l * 8);
#pragma unroll
        for (int u = 0; u < 8; ++u) acc[u] += (float)v0[u] * w0;
    }
    bf16x8 o;
#pragma unroll
    for (int u = 0; u < 8; ++u) o[u] = (bf16)acc[u];
    *(bf16x8*)(Q + (size_t)node * HDIM + l * 8) = o;
}

// ================= BN apply (coeffs precomputed) =================
__global__ __launch_bounds__(256)
void apply_bn_k(const bf16* __restrict__ X, const float* __restrict__ coef,
                bf16* __restrict__ Y, int n)
{
    __shared__ float aL[256], bL[256];
    const int tid = threadIdx.x;
    aL[tid] = coef[tid]; bL[tid] = coef[256 + tid];
    __syncthreads();
    long n4 = (long)n * 64;
    for (long i = (long)blockIdx.x * 256 + tid; i < n4; i += (long)gridDim.x * 256) {
        bf16x4 v = ((const bf16x4*)X)[i];
        int c4 = (int)(i & 63) * 4;
        float r0 = fmaf((float)v[0], aL[c4 + 0], bL[c4 + 0]); r0 = r0 > 0.f ? r0 : SLOPEV * r0;
        float r1 = fmaf((float)v[1], aL[c4 + 1], bL[c4 + 1]); r1 = r1 > 0.f ? r1 : SLOPEV * r1;
        float r2 = fmaf((float)v[2], aL[c4 + 2], bL[c4 + 2]); r2 = r2 > 0.f ? r2 : SLOPEV * r2;
        float r3 = fmaf((float)v[3], aL[c4 + 3], bL[c4 + 3]); r3 = r3 > 0.f ? r3 : SLOPEV * r3;
        bf16x4 o; o[0] = (bf16)r0; o[1] = (bf16)r1; o[2] = (bf16)r2; o[3] = (bf16)r3;
        ((bf16x4*)Y)[i] = o;
    }
}

__global__ __launch_bounds__(256)
void apply_bn4_k(bf16* X0, bf16* X1, bf16* X2, bf16* X3,
                 const float* __restrict__ coef, int n)
{
    __shared__ float aL[1024], bL[1024];
    const int tid = threadIdx.x;
#pragma unroll
    for (int q = 0; q < 4; ++q) {
        int c = q * 256 + tid;
        aL[c] = coef[c]; bL[c] = coef[1024 + c];
    }
    __syncthreads();
    bf16* Xs[4] = {X0, X1, X2, X3};
    long per = (long)n * 64;
    long stride = (long)gridDim.x * 256;
    for (int q = 0; q < 4; ++q) {
        bf16* X = Xs[q];
        int cbase = q * 256;
        for (long i = (long)blockIdx.x * 256 + tid; i < per; i += stride) {
            bf16x4 v = ((const bf16x4*)X)[i];
            int c4 = cbase + (int)(i & 63) * 4;
            float r0 = fmaf((float)v[0], aL[c4 + 0], bL[c4 + 0]); r0 = r0 > 0.f ? r0 : SLOPEV * r0;
            float r1 = fmaf((float)v[1], aL[c4 + 1], bL[c4 + 1]); r1 = r1 > 0.f ? r1 : SLOPEV * r1;
            float r2 = fmaf((float)v[2], aL[c4 + 2], bL[c4 + 2]); r2 = r2 > 0.f ? r2 : SLOPEV * r2;
            float r3 = fmaf((float)v[3], aL[c4 + 3], bL[c4 + 3]); r3 = r3 > 0.f ? r3 : SLOPEV * r3;
            bf16x4 o; o[0] = (bf16)r0; o[1] = (bf16)r1; o[2] = (bf16)r2; o[3] = (bf16)r3;
            ((bf16x4*)X)[i] = o;
        }
    }
}

// ================= host =================
struct GemmArgs {
    const bf16 *A0, *A1, *A2, *A3; int nseg, segK;
    const bf16* Wt; const float* bias; const bf16* addb;
    void *o0, *o1, *o2, *o3; int ldo, M, n_store;
    float* part; int n_stats;
};

static void gemm(hipStream_t st, const GemmArgs& a, int GY, bool store_bf16)
{
    dim3 g(a.M / 128, GY), b(256);
    if (store_bf16)
        gemm_bt_k<true><<<g, b, 0, st>>>(a.A0, a.A1, a.A2, a.A3, a.nseg, a.segK,
            a.Wt, a.bias, a.addb, a.o0, a.o1, a.o2, a.o3, a.ldo, a.n_store,
            a.part, a.n_stats);
    else
        gemm_bt_k<false><<<g, b, 0, st>>>(a.A0, a.A1, a.A2, a.A3, a.nseg, a.segK,
            a.Wt, a.bias, a.addb, a.o0, a.o1, a.o2, a.o3, a.ldo, a.n_store,
            a.part, a.n_stats);
}

extern "C" void kernel_launch(void* const* d_in, const int* in_sizes, int n_in,
                              void* d_out, int out_size, void* d_ws, size_t ws_size,
                              hipStream_t stream)
{
    const float* x       = (const float*)d_in[0];
    const int*   ei      = (const int*)d_in[1];
    const float* ew      = (const float*)d_in[2];
    const float* W_emb   = (const float*)d_in[3];
    const float* b_emb   = (const float*)d_in[4];
    const float* conv0_W = (const float*)d_in[5];
    const float* conv0_b = (const float*)d_in[6];
    const float* norm_g  = (const float*)d_in[7];
    const float* norm_b  = (const float*)d_in[8];
    const float* conv_W  = (const float*)d_in[9];
    const float* conv_b  = (const float*)d_in[10];
    const float* mlp_W1  = (const float*)d_in[11];
    const float* mlp_b1  = (const float*)d_in[12];
    const float* mlp_g   = (const float*)d_in[13];
    const float* mlp_bb  = (const float*)d_in[14];
    const float* mlp_W2  = (const float*)d_in[15];
    const float* mlp_b2  = (const float*)d_in[16];
    const float* W_out   = (const float*)d_in[17];
    const float* b_out   = (const float*)d_in[18];

    const int N = in_sizes[0] / 128;          // 50000
    const int E = in_sizes[2];                // 800000
    const int* srcI = ei;
    const int* dstI = ei + E;
    const int N_pad = ((N + 127) / 128) * 128;
    const int GY = N_pad / 128;

    const size_t NHp = (size_t)N_pad * HDIM;
    bf16* xb = (bf16*)d_ws;                      // N_pad x 128
    bf16* hb = xb + (size_t)N_pad * 128;
    bf16* cb = hb + NHp;
    bf16* p1 = cb + NHp;
    bf16* p2 = p1 + NHp;
    bf16* e1 = p2 + NHp;                         // doubles as zb
    bf16* e2 = e1 + NHp;
    bf16* wa = e2 + NHp;                         // weight arena
    bf16* Wt_emb   = wa;
    bf16* Wt_conv0 = wa + 32768;
    bf16* Wt_conv  = wa + 229376;
    bf16* Wt_mlp1  = wa + 819200;
    bf16* Wt_mlp2  = wa + 1605632;
    bf16* Wt_out   = wa + 2392064;
    float* cf_h   = (float*)(wa + 2424832);      // 512 coeffs (h BN)
    float* cf_m   = cf_h + 512;                  // 2048 coeffs (mlp BN)
    float* partb  = cf_m + 2048;                 // 2*GY*1024 floats max (3.2 MB)
    int*   rowptr = (int*)(partb + 2 * (size_t)GY * 1024);
    int*   wp     = rowptr + (N + 1);
    int*   col    = wp + N;
    float* wgt    = (float*)(col + E);

    const float invn = 1.0f / (float)N;
    dim3 pg((N + 7) / 8), pb(256);

    // ---- CSR build ----
    hipMemsetAsync(wp, 0, (size_t)N * 4, stream);
    deg_k<<<dim3((E + 255) / 256), dim3(256), 0, stream>>>(dstI, wp, E);
    scan_k<<<dim3(1), dim3(1024), 0, stream>>>(wp, rowptr, N);
    reorder_k<<<dim3((E + 255) / 256), dim3(256), 0, stream>>>(srcI, dstI, ew, wp, col, wgt, E);

    // ---- convert inputs/weights ----
    cvt_bf_k<<<dim3((N * 32 + 255) / 256), dim3(256), 0, stream>>>(x, xb, (long)N * 32);
    transpose_cvt_k<<<dim3(8, 4, 1), dim3(256), 0, stream>>>(W_emb, Wt_emb, 128, 256, 1);
    transpose_cvt_k<<<dim3(8, 8, 3), dim3(256), 0, stream>>>(conv0_W, Wt_conv0, 256, 256, 3);
    transpose_cvt_k<<<dim3(8, 8, 9), dim3(256), 0, stream>>>(conv_W, Wt_conv, 256, 256, 3);
    transpose_cvt_k<<<dim3(32, 8, 3), dim3(256), 0, stream>>>(mlp_W1, Wt_mlp1, 256, 1024, 1);
    transpose_cvt_k<<<dim3(8, 32, 3), dim3(256), 0, stream>>>(mlp_W2, Wt_mlp2, 1024, 256, 1);
    transpose_cvt_k<<<dim3(4, 8, 1), dim3(256), 0, stream>>>(W_out, Wt_out, 256, 128, 1);

    // ---- embed: cb = bf16(x @ W_emb + b_emb) ----
    {
        GemmArgs a{xb, xb, xb, xb, 1, 128, Wt_emb, b_emb, nullptr,
                   cb, cb, cb, cb, HDIM, 256, N_pad, nullptr, 0};
        gemm(stream, a, GY, true);
    }

    // ---- conv0: hb = [cb | A.cb | A^2.cb] @ Wt_conv0 + b ; partials -> cf_h ----
    spmm_pull_k<<<pg, pb, 0, stream>>>(cb, rowptr, col, wgt, p1, N);
    spmm_pull_k<<<pg, pb, 0, stream>>>(p1, rowptr, col, wgt, p2, N);
    {
        GemmArgs a{cb, p1, p2, p2, 3, 256, Wt_conv0, conv0_b, nullptr,
                   hb, hb, hb, hb, HDIM, 256, N_pad, partb, N};
        gemm(stream, a, GY, true);
    }
    finalize_k<<<dim3(256), dim3(256), 0, stream>>>(partb, GY, 256, norm_g, norm_b, cf_h, invn);

    for (int l = 0; l < 3; ++l) {
        // zb(e1) = leaky(bn(hb)) using precomputed coeffs
        apply_bn_k<<<dim3(1024), dim3(256), 0, stream>>>(hb, cf_h, e1, N);

        // conv: cb = [zb | A.zb | A^2.zb] @ Wl + b
        spmm_pull_k<<<pg, pb, 0, stream>>>(e1, rowptr, col, wgt, p1, N);
        spmm_pull_k<<<pg, pb, 0, stream>>>(p1, rowptr, col, wgt, p2, N);
        {
            GemmArgs a{e1, p1, p2, p2, 3, 256, Wt_conv + (size_t)l * 196608,
                       conv_b + l * 256, nullptr, cb, cb, cb, cb, HDIM, 256, N_pad,
                       nullptr, 0};
            gemm(stream, a, GY, true);
        }

        // W1: {p1,p2,e1,e2} = cb @ W1 + b1 ; partials -> cf_m
        {
            GemmArgs a{cb, cb, cb, cb, 1, 256, Wt_mlp1 + (size_t)l * 262144,
                       mlp_b1 + (size_t)l * 1024, nullptr, p1, p2, e1, e2, HDIM, 1024,
                       N_pad, partb, N};
            gemm(stream, a, GY, true);
        }
        finalize_k<<<dim3(1024), dim3(256), 0, stream>>>(partb, GY, 1024,
                                                         mlp_g + (size_t)l * 1024,
                                                         mlp_bb + (size_t)l * 1024, cf_m, invn);

        // hidden = leaky(bn(hidden)) in-place
        apply_bn4_k<<<dim3(2048), dim3(256), 0, stream>>>(p1, p2, e1, e2, cf_m, N);

        // W2: hb += hidden @ W2 + b2 ; partials for next layer's h-BN (if any)
        {
            GemmArgs a{p1, p2, e1, e2, 4, 256, Wt_mlp2 + (size_t)l * 262144,
                       mlp_b2 + l * 256, hb, hb, hb, hb, hb, HDIM, 256, N_pad,
                       (l < 2) ? partb : nullptr, N};
            gemm(stream, a, GY, true);
        }
        if (l < 2)
            finalize_k<<<dim3(256), dim3(256), 0, stream>>>(partb, GY, 256,
                                                            norm_g + (l + 1) * 256,
                                                            norm_b + (l + 1) * 256, cf_h, invn);
    }

    // ---- out = hb @ W_out + b_out (f32) ----
    {
        GemmArgs a{hb, hb, hb, hb, 1, 256, Wt_out, b_out, nullptr,
                   d_out, d_out, d_out, d_out, 128, 128, N, nullptr, 0};
        gemm(stream, a, GY, false);
    }
}

// Round 10
// 1489.292 us; speedup vs baseline: 1.6952x; 1.0361x over previous
//
#include <hip/hip_runtime.h>

#define HDIM 256
#define EPSV 1e-5f
#define SLOPEV 0.01f

typedef __bf16 bf16;
typedef bf16  bf16x8 __attribute__((ext_vector_type(8)));
typedef bf16  bf16x4 __attribute__((ext_vector_type(4)));
typedef float f32x4  __attribute__((ext_vector_type(4)));

#define GLD16(g, l) __builtin_amdgcn_global_load_lds( \
    (const __attribute__((address_space(1))) void*)(g), \
    (__attribute__((address_space(3))) void*)(l), 16, 0, 0)

// ================= MFMA GEMM (BK=64) =================
// out = concat_k(A0..A_{nseg-1}) * Wt^T + bias (+addb residual).
// Coalesced bf16 epilogue via LDS staging. Optional per-rowblock column
// partial sums (NO atomics): part[by][colg] sum, part[GY+by][colg] sumsq.
template<bool STORE_BF16>
__global__ __launch_bounds__(256)
void gemm_bt_k(const bf16* A0, const bf16* A1, const bf16* A2, const bf16* A3,
               int nseg, int segK,
               const bf16* __restrict__ Wt,
               const float* __restrict__ bias, const bf16* __restrict__ addb,
               void* out0, void* out1, void* out2, void* out3, int ldo,
               int n_store, float* part, int n_stats)
{
    __shared__ char smem[32768];
    bf16* As = (bf16*)smem;               // [128][64] bf16, 16 KB
    bf16* Bs = (bf16*)(smem + 16384);     // [128][64] bf16, 16 KB

    const int tid = threadIdx.x;
    const int wave = tid >> 6, lane = tid & 63;
    const int quad = lane >> 4, l16 = lane & 15;
    const int waveM = (wave >> 1) * 64, waveN = (wave & 1) * 64;
    const int bm = blockIdx.y * 128, bn = blockIdx.x * 128;
    const int K = nseg * segK;

    const bf16* segs[4] = {A0, A1, A2, A3};
    const int srow = tid >> 3;            // 0..31
    const int skof = (tid & 7) * 8;       // 0..56
    char* lA = (char*)As + wave * 1024;   // + q*4096
    char* lB = (char*)Bs + wave * 1024;
    const bf16* pa = As + (waveM + l16) * 64 + quad * 8;
    const bf16* pb = Bs + (waveN + l16) * 64 + quad * 8;

    f32x4 acc[4][4] = {};

    for (int s = 0; s < nseg; ++s) {
        const bf16* gA = segs[s] + (size_t)(bm + srow) * segK + skof;
        const bf16* gB = Wt + (size_t)(bn + srow) * K + s * segK + skof;
        const size_t offA = (size_t)32 * segK;   // 32 rows
        const size_t offB = (size_t)32 * K;
        for (int kt = 0; kt < segK; kt += 64) {
            GLD16(gA,            lA);
            GLD16(gA + offA,     lA + 4096);
            GLD16(gA + 2 * offA, lA + 8192);
            GLD16(gA + 3 * offA, lA + 12288);
            GLD16(gB,            lB);
            GLD16(gB + offB,     lB + 4096);
            GLD16(gB + 2 * offB, lB + 8192);
            GLD16(gB + 3 * offB, lB + 12288);
            gA += 64; gB += 64;
            __syncthreads();

#pragma unroll
            for (int ks = 0; ks < 2; ++ks) {
                const bf16* pak = pa + ks * 32;
                const bf16* pbk = pb + ks * 32;
                bf16x8 a0 = *(const bf16x8*)(pak);
                bf16x8 a1 = *(const bf16x8*)(pak + 16 * 64);
                bf16x8 a2 = *(const bf16x8*)(pak + 32 * 64);
                bf16x8 a3 = *(const bf16x8*)(pak + 48 * 64);
                bf16x8 b0 = *(const bf16x8*)(pbk);
                bf16x8 b1 = *(const bf16x8*)(pbk + 16 * 64);
                bf16x8 b2 = *(const bf16x8*)(pbk + 32 * 64);
                bf16x8 b3 = *(const bf16x8*)(pbk + 48 * 64);

                acc[0][0] = __builtin_amdgcn_mfma_f32_16x16x32_bf16(a0, b0, acc[0][0], 0, 0, 0);
                acc[0][1] = __builtin_amdgcn_mfma_f32_16x16x32_bf16(a0, b1, acc[0][1], 0, 0, 0);
                acc[0][2] = __builtin_amdgcn_mfma_f32_16x16x32_bf16(a0, b2, acc[0][2], 0, 0, 0);
                acc[0][3] = __builtin_amdgcn_mfma_f32_16x16x32_bf16(a0, b3, acc[0][3], 0, 0, 0);
                acc[1][0] = __builtin_amdgcn_mfma_f32_16x16x32_bf16(a1, b0, acc[1][0], 0, 0, 0);
                acc[1][1] = __builtin_amdgcn_mfma_f32_16x16x32_bf16(a1, b1, acc[1][1], 0, 0, 0);
                acc[1][2] = __builtin_amdgcn_mfma_f32_16x16x32_bf16(a1, b2, acc[1][2], 0, 0, 0);
                acc[1][3] = __builtin_amdgcn_mfma_f32_16x16x32_bf16(a1, b3, acc[1][3], 0, 0, 0);
                acc[2][0] = __builtin_amdgcn_mfma_f32_16x16x32_bf16(a2, b0, acc[2][0], 0, 0, 0);
                acc[2][1] = __builtin_amdgcn_mfma_f32_16x16x32_bf16(a2, b1, acc[2][1], 0, 0, 0);
                acc[2][2] = __builtin_amdgcn_mfma_f32_16x16x32_bf16(a2, b2, acc[2][2], 0, 0, 0);
                acc[2][3] = __builtin_amdgcn_mfma_f32_16x16x32_bf16(a2, b3, acc[2][3], 0, 0, 0);
                acc[3][0] = __builtin_amdgcn_mfma_f32_16x16x32_bf16(a3, b0, acc[3][0], 0, 0, 0);
                acc[3][1] = __builtin_amdgcn_mfma_f32_16x16x32_bf16(a3, b1, acc[3][1], 0, 0, 0);
                acc[3][2] = __builtin_amdgcn_mfma_f32_16x16x32_bf16(a3, b2, acc[3][2], 0, 0, 0);
                acc[3][3] = __builtin_amdgcn_mfma_f32_16x16x32_bf16(a3, b3, acc[3][3], 0, 0, 0);
            }
            __syncthreads();
        }
    }

    float bv[4];
#pragma unroll
    for (int j = 0; j < 4; ++j)
        bv[j] = bias ? bias[bn + waveN + j * 16 + l16] : 0.f;
#pragma unroll
    for (int i = 0; i < 4; ++i)
#pragma unroll
        for (int j = 0; j < 4; ++j)
#pragma unroll
            for (int r = 0; r < 4; ++r)
                acc[i][j][r] += bv[j];

    void* outs[4] = {out0, out1, out2, out3};

    if (STORE_BF16) {
        // per-wave 32x64 staging tile, row stride 68 bf16
        char* stg = smem + wave * 4352;
        float s8[8] = {}, q8[8] = {};
        const int rsel = lane >> 3, csel = lane & 7;
#pragma unroll
        for (int ih = 0; ih < 2; ++ih) {
            __syncthreads();
#pragma unroll
            for (int iw = 0; iw < 2; ++iw) {
                int i = ih * 2 + iw;
#pragma unroll
                for (int j = 0; j < 4; ++j)
#pragma unroll
                    for (int r = 0; r < 4; ++r)
                        *(bf16*)(stg + ((iw * 16 + quad * 4 + r) * 68 + j * 16 + l16) * 2)
                            = (bf16)acc[i][j][r];
            }
            __syncthreads();
#pragma unroll
            for (int rr = 0; rr < 4; ++rr) {
                int rl = rsel + rr * 8;
                bf16x4 lo = *(const bf16x4*)(stg + (rl * 68 + csel * 8) * 2);
                bf16x4 hi = *(const bf16x4*)(stg + (rl * 68 + csel * 8 + 4) * 2);
                int rowg = bm + waveM + ih * 32 + rl;
                int colg = bn + waveN + csel * 8;
                int cseg = colg >> 8, cloc = colg & 255;
                size_t idx = (size_t)rowg * ldo + cloc;
                float f[8];
#pragma unroll
                for (int u = 0; u < 4; ++u) { f[u] = (float)lo[u]; f[4 + u] = (float)hi[u]; }
                if (addb) {
                    bf16x8 o = *(const bf16x8*)(addb + idx);
#pragma unroll
                    for (int u = 0; u < 8; ++u) f[u] += (float)o[u];
                }
                bf16x8 w;
#pragma unroll
                for (int u = 0; u < 8; ++u) w[u] = (bf16)f[u];
                if (rowg < n_store) *(bf16x8*)((bf16*)outs[cseg] + idx) = w;
                if (part && rowg < n_stats) {
#pragma unroll
                    for (int u = 0; u < 8; ++u) { s8[u] += f[u]; q8[u] += f[u] * f[u]; }
                }
            }
        }
        if (part) {
#pragma unroll
            for (int m = 8; m <= 32; m <<= 1)
#pragma unroll
                for (int u = 0; u < 8; ++u) {
                    s8[u] += __shfl_xor(s8[u], m, 64);
                    q8[u] += __shfl_xor(q8[u], m, 64);
                }
            __syncthreads();
            float* Ls = (float*)smem;          // [4][64]
            float* Lq = Ls + 256;              // [4][64]
            if (rsel == 0) {
#pragma unroll
                for (int u = 0; u < 8; ++u) {
                    Ls[wave * 64 + csel * 8 + u] = s8[u];
                    Lq[wave * 64 + csel * 8 + u] = q8[u];
                }
            }
            __syncthreads();
            if (tid < 128) {
                int hi = tid >> 6, c6 = tid & 63;
                float s = Ls[hi * 64 + c6] + Ls[(hi + 2) * 64 + c6];
                float q = Lq[hi * 64 + c6] + Lq[(hi + 2) * 64 + c6];
                int Mtot = gridDim.x * 128;
                int colg = bn + tid;
                part[(size_t)blockIdx.y * Mtot + colg] = s;
                part[(size_t)(gridDim.y + blockIdx.y) * Mtot + colg] = q;
            }
        }
    } else {
#pragma unroll
        for (int i = 0; i < 4; ++i)
#pragma unroll
            for (int j = 0; j < 4; ++j) {
                int colg = bn + waveN + j * 16 + l16;
                int cseg = colg >> 8, cloc = colg & 255;
#pragma unroll
                for (int r = 0; r < 4; ++r) {
                    int rowg = bm + waveM + i * 16 + quad * 4 + r;
                    if (rowg < n_store)
                        ((float*)outs[cseg])[(size_t)rowg * ldo + cloc] = acc[i][j][r];
                }
            }
    }
}

// ================= finalize: one block per column, tree reduce =================
__global__ __launch_bounds__(256)
void finalize_k(const float* __restrict__ part, int GY, int M,
                const float* __restrict__ g, const float* __restrict__ bb,
                float* __restrict__ coef, float invn)
{
    const int c = blockIdx.x;
    const int t = threadIdx.x;
    float s = 0.f, q = 0.f;
    const float* ps = part + c;
    const float* pq = part + (size_t)GY * M + c;
    for (int i = t; i < GY; i += 256) {
        s += ps[(size_t)i * M];
        q += pq[(size_t)i * M];
    }
#pragma unroll
    for (int m = 1; m <= 32; m <<= 1) {
        s += __shfl_xor(s, m, 64);
        q += __shfl_xor(q, m, 64);
    }
    __shared__ float Ls[4], Lq[4];
    const int w = t >> 6, l = t & 63;
    if (l == 0) { Ls[w] = s; Lq[w] = q; }
    __syncthreads();
    if (t == 0) {
        s = Ls[0] + Ls[1] + Ls[2] + Ls[3];
        q = Lq[0] + Lq[1] + Lq[2] + Lq[3];
        float mean = s * invn;
        float var  = q * invn - mean * mean;
        float a = g[c] * rsqrtf(var + EPSV);
        coef[c]     = a;
        coef[M + c] = bb[c] - mean * a;
    }
}

// ================= transpose+convert =================
__global__ __launch_bounds__(256)
void transpose_cvt_k(const float* __restrict__ src, bf16* __restrict__ dst,
                     int Kseg, int M, int G)
{
    __shared__ float t[32][33];
    const int z = blockIdx.z;
    src += (size_t)z * Kseg * M;
    const int ldd = G * Kseg;
    dst += (size_t)(z / G) * M * ldd + (size_t)(z % G) * Kseg;
    const int tM = blockIdx.x * 32, tK = blockIdx.y * 32;
    const int tx = threadIdx.x & 31, ty = threadIdx.x >> 5;
#pragma unroll
    for (int r = 0; r < 4; ++r)
        t[ty + r * 8][tx] = src[(size_t)(tK + ty + r * 8) * M + tM + tx];
    __syncthreads();
#pragma unroll
    for (int r = 0; r < 4; ++r)
        dst[(size_t)(tM + ty + r * 8) * ldd + tK + tx] = (bf16)t[tx][ty + r * 8];
}

__global__ __launch_bounds__(256)
void cvt_bf_k(const float* __restrict__ src, bf16* __restrict__ dst, long n4)
{
    long i = (long)blockIdx.x * blockDim.x + threadIdx.x;
    if (i >= n4) return;
    float4 v = ((const float4*)src)[i];
    bf16x4 o; o[0] = (bf16)v.x; o[1] = (bf16)v.y; o[2] = (bf16)v.z; o[3] = (bf16)v.w;
    ((bf16x4*)dst)[i] = o;
}

// ================= CSR build (parallel scan) =================
__global__ __launch_bounds__(256)
void deg_k(const int* __restrict__ dst, int* __restrict__ deg, int E)
{
    int e = blockIdx.x * blockDim.x + threadIdx.x;
    if (e < E) atomicAdd(&deg[dst[e]], 1);
}

// per-block sums of deg (256 per block)
__global__ __launch_bounds__(256)
void blocksum_k(const int* __restrict__ deg, int* __restrict__ bsum, int N)
{
    int i = blockIdx.x * 256 + threadIdx.x;
    int v = (i < N) ? deg[i] : 0;
#pragma unroll
    for (int m = 1; m <= 32; m <<= 1) v += __shfl_xor(v, m, 64);
    __shared__ int Ls[4];
    if ((threadIdx.x & 63) == 0) Ls[threadIdx.x >> 6] = v;
    __syncthreads();
    if (threadIdx.x == 0) bsum[blockIdx.x] = Ls[0] + Ls[1] + Ls[2] + Ls[3];
}

// 1 block: exclusive scan of nb block sums -> boff
__global__ __launch_bounds__(256)
void topscan_k(const int* __restrict__ bsum, int* __restrict__ boff, int nb)
{
    __shared__ int s[256];
    int t = threadIdx.x;
    int v = (t < nb) ? bsum[t] : 0;
    s[t] = v;
    __syncthreads();
    for (int off = 1; off < 256; off <<= 1) {
        int u = (t >= off) ? s[t - off] : 0;
        __syncthreads();
        s[t] += u;
        __syncthreads();
    }
    if (t < nb) boff[t] = s[t] - v;   // exclusive
}

// per-block: scan own 256 degs, add boff -> rowptr[i+1], wp[i] (exclusive)
__global__ __launch_bounds__(256)
void scatterscan_k(int* __restrict__ deg_wp, const int* __restrict__ boff,
                   int* __restrict__ rowptr, int N)
{
    __shared__ int s[256];
    int t = threadIdx.x;
    int i = blockIdx.x * 256 + t;
    int v = (i < N) ? deg_wp[i] : 0;
    s[t] = v;
    __syncthreads();
    for (int off = 1; off < 256; off <<= 1) {
        int u = (t >= off) ? s[t - off] : 0;
        __syncthreads();
        s[t] += u;
        __syncthreads();
    }
    if (i < N) {
        int incl = s[t] + boff[blockIdx.x];
        rowptr[i + 1] = incl;
        deg_wp[i] = incl - v;     // exclusive -> reorder write ptr
        if (i == 0) rowptr[0] = 0;
    }
}

__global__ __launch_bounds__(256)
void reorder_k(const int* __restrict__ src, const int* __restrict__ dst,
               const float* __restrict__ ew, int* __restrict__ wp,
               int* __restrict__ col, float* __restrict__ wgt, int E)
{
    int e = blockIdx.x * blockDim.x + threadIdx.x;
    if (e >= E) return;
    int d = dst[e];
    int pos = atomicAdd(&wp[d], 1);
    col[pos] = src[e];
    wgt[pos] = ew[e];
}

// ================= pull SpMM: half-wave (32 lanes x bf16x8) per node =================
__global__ __launch_bounds__(256)
void spmm_pull_k(const bf16* __restrict__ P, const int* __restrict__ rowptr,
                 const int* __restrict__ col, const float* __restrict__ wgt,
                 bf16* __restrict__ Q, int N)
{
    int node = blockIdx.x * 8 + (threadIdx.x >> 5);
    int l = threadIdx.x & 31;
    if (node >= N) return;
    int e = rowptr[node], end = rowptr[node + 1];
    float acc[8] = {};
    for (; e + 1 < end; e += 2) {
        int   s0 = col[e], s1 = col[e + 1];
        float w0 = wgt[e], w1 = wgt[e + 1];
        bf16x8 v0 = *(const bf16x8*)(P + (size_t)s0 * HDIM + l * 8);
        bf16x8 v1 = *(const bf16x8*)(P + (size_t)s1 * HDIM + l * 8);
#pragma unroll
        for (int u = 0; u < 8; ++u)
            acc[u] += (float)v0[u] * w0 + (float)v1[u] * w1;
    }
    if (e < end) {
        int s0 = col[e]; float w0 = wgt[e];
        bf16x8 v0 = *(const bf16x8*)(P + (size_t)s0 * HDIM + l * 8);
#pragma unroll
        for (int u = 0; u < 8; ++u) acc[u] += (float)v0[u] * w0;
    }
    bf16x8 o;
#pragma unroll
    for (int u = 0; u < 8; ++u) o[u] = (bf16)acc[u];
    *(bf16x8*)(Q + (size_t)node * HDIM + l * 8) = o;
}

// ================= BN apply (coeffs precomputed) =================
__global__ __launch_bounds__(256)
void apply_bn_k(const bf16* __restrict__ X, const float* __restrict__ coef,
                bf16* __restrict__ Y, int n)
{
    __shared__ float aL[256], bL[256];
    const int tid = threadIdx.x;
    aL[tid] = coef[tid]; bL[tid] = coef[256 + tid];
    __syncthreads();
    long n4 = (long)n * 64;
    for (long i = (long)blockIdx.x * 256 + tid; i < n4; i += (long)gridDim.x * 256) {
        bf16x4 v = ((const bf16x4*)X)[i];
        int c4 = (int)(i & 63) * 4;
        float r0 = fmaf((float)v[0], aL[c4 + 0], bL[c4 + 0]); r0 = r0 > 0.f ? r0 : SLOPEV * r0;
        float r1 = fmaf((float)v[1], aL[c4 + 1], bL[c4 + 1]); r1 = r1 > 0.f ? r1 : SLOPEV * r1;
        float r2 = fmaf((float)v[2], aL[c4 + 2], bL[c4 + 2]); r2 = r2 > 0.f ? r2 : SLOPEV * r2;
        float r3 = fmaf((float)v[3], aL[c4 + 3], bL[c4 + 3]); r3 = r3 > 0.f ? r3 : SLOPEV * r3;
        bf16x4 o; o[0] = (bf16)r0; o[1] = (bf16)r1; o[2] = (bf16)r2; o[3] = (bf16)r3;
        ((bf16x4*)Y)[i] = o;
    }
}

__global__ __launch_bounds__(256)
void apply_bn4_k(bf16* X0, bf16* X1, bf16* X2, bf16* X3,
                 const float* __restrict__ coef, int n)
{
    __shared__ float aL[1024], bL[1024];
    const int tid = threadIdx.x;
#pragma unroll
    for (int q = 0; q < 4; ++q) {
        int c = q * 256 + tid;
        aL[c] = coef[c]; bL[c] = coef[1024 + c];
    }
    __syncthreads();
    bf16* Xs[4] = {X0, X1, X2, X3};
    long per = (long)n * 64;
    long stride = (long)gridDim.x * 256;
    for (int q = 0; q < 4; ++q) {
        bf16* X = Xs[q];
        int cbase = q * 256;
        for (long i = (long)blockIdx.x * 256 + tid; i < per; i += stride) {
            bf16x4 v = ((const bf16x4*)X)[i];
            int c4 = cbase + (int)(i & 63) * 4;
            float r0 = fmaf((float)v[0], aL[c4 + 0], bL[c4 + 0]); r0 = r0 > 0.f ? r0 : SLOPEV * r0;
            float r1 = fmaf((float)v[1], aL[c4 + 1], bL[c4 + 1]); r1 = r1 > 0.f ? r1 : SLOPEV * r1;
            float r2 = fmaf((float)v[2], aL[c4 + 2], bL[c4 + 2]); r2 = r2 > 0.f ? r2 : SLOPEV * r2;
            float r3 = fmaf((float)v[3], aL[c4 + 3], bL[c4 + 3]); r3 = r3 > 0.f ? r3 : SLOPEV * r3;
            bf16x4 o; o[0] = (bf16)r0; o[1] = (bf16)r1; o[2] = (bf16)r2; o[3] = (bf16)r3;
            ((bf16x4*)X)[i] = o;
        }
    }
}

// ================= host =================
struct GemmArgs {
    const bf16 *A0, *A1, *A2, *A3; int nseg, segK;
    const bf16* Wt; const float* bias; const bf16* addb;
    void *o0, *o1, *o2, *o3; int ldo, M, n_store;
    float* part; int n_stats;
};

static void gemm(hipStream_t st, const GemmArgs& a, int GY, bool store_bf16)
{
    dim3 g(a.M / 128, GY), b(256);
    if (store_bf16)
        gemm_bt_k<true><<<g, b, 0, st>>>(a.A0, a.A1, a.A2, a.A3, a.nseg, a.segK,
            a.Wt, a.bias, a.addb, a.o0, a.o1, a.o2, a.o3, a.ldo, a.n_store,
            a.part, a.n_stats);
    else
        gemm_bt_k<false><<<g, b, 0, st>>>(a.A0, a.A1, a.A2, a.A3, a.nseg, a.segK,
            a.Wt, a.bias, a.addb, a.o0, a.o1, a.o2, a.o3, a.ldo, a.n_store,
            a.part, a.n_stats);
}

extern "C" void kernel_launch(void* const* d_in, const int* in_sizes, int n_in,
                              void* d_out, int out_size, void* d_ws, size_t ws_size,
                              hipStream_t stream)
{
    const float* x       = (const float*)d_in[0];
    const int*   ei      = (const int*)d_in[1];
    const float* ew      = (const float*)d_in[2];
    const float* W_emb   = (const float*)d_in[3];
    const float* b_emb   = (const float*)d_in[4];
    const float* conv0_W = (const float*)d_in[5];
    const float* conv0_b = (const float*)d_in[6];
    const float* norm_g  = (const float*)d_in[7];
    const float* norm_b  = (const float*)d_in[8];
    const float* conv_W  = (const float*)d_in[9];
    const float* conv_b  = (const float*)d_in[10];
    const float* mlp_W1  = (const float*)d_in[11];
    const float* mlp_b1  = (const float*)d_in[12];
    const float* mlp_g   = (const float*)d_in[13];
    const float* mlp_bb  = (const float*)d_in[14];
    const float* mlp_W2  = (const float*)d_in[15];
    const float* mlp_b2  = (const float*)d_in[16];
    const float* W_out   = (const float*)d_in[17];
    const float* b_out   = (const float*)d_in[18];

    const int N = in_sizes[0] / 128;          // 50000
    const int E = in_sizes[2];                // 800000
    const int* srcI = ei;
    const int* dstI = ei + E;
    const int N_pad = ((N + 127) / 128) * 128;
    const int GY = N_pad / 128;
    const int NB = (N + 255) / 256;           // scan blocks (<=256)

    const size_t NHp = (size_t)N_pad * HDIM;
    bf16* xb = (bf16*)d_ws;                      // N_pad x 128
    bf16* hb = xb + (size_t)N_pad * 128;
    bf16* cb = hb + NHp;
    bf16* p1 = cb + NHp;
    bf16* p2 = p1 + NHp;
    bf16* e1 = p2 + NHp;                         // doubles as zb
    bf16* e2 = e1 + NHp;
    bf16* wa = e2 + NHp;                         // weight arena
    bf16* Wt_emb   = wa;
    bf16* Wt_conv0 = wa + 32768;
    bf16* Wt_conv  = wa + 229376;
    bf16* Wt_mlp1  = wa + 819200;
    bf16* Wt_mlp2  = wa + 1605632;
    bf16* Wt_out   = wa + 2392064;
    float* cf_h   = (float*)(wa + 2424832);      // 512 coeffs (h BN)
    float* cf_m   = cf_h + 512;                  // 2048 coeffs (mlp BN)
    float* partb  = cf_m + 2048;                 // 2*GY*1024 floats max
    int*   rowptr = (int*)(partb + 2 * (size_t)GY * 1024);
    int*   wp     = rowptr + (N + 1);
    int*   col    = wp + N;
    float* wgt    = (float*)(col + E);
    int*   bsum   = (int*)(wgt + E);             // 256
    int*   boff   = bsum + 256;                  // 256

    const float invn = 1.0f / (float)N;
    dim3 pg((N + 7) / 8), pb(256);

    // ---- CSR build (parallel scan) ----
    hipMemsetAsync(wp, 0, (size_t)N * 4, stream);
    deg_k<<<dim3((E + 255) / 256), dim3(256), 0, stream>>>(dstI, wp, E);
    blocksum_k<<<dim3(NB), dim3(256), 0, stream>>>(wp, bsum, N);
    topscan_k<<<dim3(1), dim3(256), 0, stream>>>(bsum, boff, NB);
    scatterscan_k<<<dim3(NB), dim3(256), 0, stream>>>(wp, boff, rowptr, N);
    reorder_k<<<dim3((E + 255) / 256), dim3(256), 0, stream>>>(srcI, dstI, ew, wp, col, wgt, E);

    // ---- convert inputs/weights ----
    cvt_bf_k<<<dim3((N * 32 + 255) / 256), dim3(256), 0, stream>>>(x, xb, (long)N * 32);
    transpose_cvt_k<<<dim3(8, 4, 1), dim3(256), 0, stream>>>(W_emb, Wt_emb, 128, 256, 1);
    transpose_cvt_k<<<dim3(8, 8, 3), dim3(256), 0, stream>>>(conv0_W, Wt_conv0, 256, 256, 3);
    transpose_cvt_k<<<dim3(8, 8, 9), dim3(256), 0, stream>>>(conv_W, Wt_conv, 256, 256, 3);
    transpose_cvt_k<<<dim3(32, 8, 3), dim3(256), 0, stream>>>(mlp_W1, Wt_mlp1, 256, 1024, 1);
    transpose_cvt_k<<<dim3(8, 32, 3), dim3(256), 0, stream>>>(mlp_W2, Wt_mlp2, 1024, 256, 1);
    transpose_cvt_k<<<dim3(4, 8, 1), dim3(256), 0, stream>>>(W_out, Wt_out, 256, 128, 1);

    // ---- embed: cb = bf16(x @ W_emb + b_emb) ----
    {
        GemmArgs a{xb, xb, xb, xb, 1, 128, Wt_emb, b_emb, nullptr,
                   cb, cb, cb, cb, HDIM, 256, N_pad, nullptr, 0};
        gemm(stream, a, GY, true);
    }

    // ---- conv0: hb = [cb | A.cb | A^2.cb] @ Wt_conv0 + b ; partials -> cf_h ----
    spmm_pull_k<<<pg, pb, 0, stream>>>(cb, rowptr, col, wgt, p1, N);
    spmm_pull_k<<<pg, pb, 0, stream>>>(p1, rowptr, col, wgt, p2, N);
    {
        GemmArgs a{cb, p1, p2, p2, 3, 256, Wt_conv0, conv0_b, nullptr,
                   hb, hb, hb, hb, HDIM, 256, N_pad, partb, N};
        gemm(stream, a, GY, true);
    }
    finalize_k<<<dim3(256), dim3(256), 0, stream>>>(partb, GY, 256, norm_g, norm_b, cf_h, invn);

    for (int l = 0; l < 3; ++l) {
        // zb(e1) = leaky(bn(hb)) using precomputed coeffs
        apply_bn_k<<<dim3(1024), dim3(256), 0, stream>>>(hb, cf_h, e1, N);

        // conv: cb = [zb | A.zb | A^2.zb] @ Wl + b
        spmm_pull_k<<<pg, pb, 0, stream>>>(e1, rowptr, col, wgt, p1, N);
        spmm_pull_k<<<pg, pb, 0, stream>>>(p1, rowptr, col, wgt, p2, N);
        {
            GemmArgs a{e1, p1, p2, p2, 3, 256, Wt_conv + (size_t)l * 196608,
                       conv_b + l * 256, nullptr, cb, cb, cb, cb, HDIM, 256, N_pad,
                       nullptr, 0};
            gemm(stream, a, GY, true);
        }

        // W1: {p1,p2,e1,e2} = cb @ W1 + b1 ; partials -> cf_m
        {
            GemmArgs a{cb, cb, cb, cb, 1, 256, Wt_mlp1 + (size_t)l * 262144,
                       mlp_b1 + (size_t)l * 1024, nullptr, p1, p2, e1, e2, HDIM, 1024,
                       N_pad, partb, N};
            gemm(stream, a, GY, true);
        }
        finalize_k<<<dim3(1024), dim3(256), 0, stream>>>(partb, GY, 1024,
                                                         mlp_g + (size_t)l * 1024,
                                                         mlp_bb + (size_t)l * 1024, cf_m, invn);

        // hidden = leaky(bn(hidden)) in-place
        apply_bn4_k<<<dim3(2048), dim3(256), 0, stream>>>(p1, p2, e1, e2, cf_m, N);

        // W2: hb += hidden @ W2 + b2 ; partials for next layer's h-BN (if any)
        {
            GemmArgs a{p1, p2, e1, e2, 4, 256, Wt_mlp2 + (size_t)l * 262144,
                       mlp_b2 + l * 256, hb, hb, hb, hb, hb, HDIM, 256, N_pad,
                       (l < 2) ? partb : nullptr, N};
            gemm(stream, a, GY, true);
        }
        if (l < 2)
            finalize_k<<<dim3(256), dim3(256), 0, stream>>>(partb, GY, 256,
                                                            norm_g + (l + 1) * 256,
                                                            norm_b + (l + 1) * 256, cf_h, invn);
    }

    // ---- out = hb @ W_out + b_out (f32) ----
    {
        GemmArgs a{hb, hb, hb, hb, 1, 256, Wt_out, b_out, nullptr,
                   d_out, d_out, d_out, d_out, 128, 128, N, nullptr, 0};
        gemm(stream, a, GY, false);
    }
}